// Round 17
// baseline (258.538 us; speedup 1.0000x reference)
//
#include <hip/hip_runtime.h>
#include <cstddef>

#define GG 2048
#define PP 18
#define NNODE (GG*PP)      // 36864
#define EPG 306            // directed edges per graph (17*18)
#define F1 128             // H1*C1
#define F2 256             // H2*C2
#define ASX 20             // alpha row stride: alpha[(d*4+h)*ASX + s]
#define INF 6
// gat1: xl f32 padded layout
#define HP1 36             // xl head stride (f32); also wa1 head stride (float2)
#define XR1 144            // xl row stride; mod 32 = 16
// gat1: xr bf16-PAIR layout (u32 units)
#define HPR1 20
#define XRR1 80            // mod 32 = 16
// gat2: xl f32 padded layout
#define HP2 68
#define XR2 272            // mod 32 = 16
// gat2: xr bf16-PAIR layout (u32 units)
#define HPP 36
#define XRP 144            // mod 32 = 16

typedef unsigned short u16;
typedef unsigned int u32;
typedef __attribute__((ext_vector_type(8))) short short8;   // 8 bf16
typedef __attribute__((ext_vector_type(4))) float f32x4;

__device__ __forceinline__ float lrelu(float v) { return fmaxf(v, 0.01f*v); }

__device__ __forceinline__ u16 f2b(float x) {            // fp32 -> bf16 RNE
    union { float f; unsigned u; } c; c.f = x;
    unsigned r = c.u + 0x7FFF + ((c.u >> 16) & 1);
    return (u16)(r >> 16);
}
__device__ __forceinline__ float b2f(u16 v) {
    union { unsigned u; float f; } c; c.u = ((unsigned)v) << 16;
    return c.f;
}
__device__ __forceinline__ float bpk_lo(u32 u) { return __uint_as_float(u << 16); }
__device__ __forceinline__ float bpk_hi(u32 u) { return __uint_as_float(u & 0xffff0000u); }

// ================= layer-1 projection: xlr1 = bf16([x@W1l+b1l | x@W1r+b1r]) =================
// 32 nodes/block; thread owns output column j (weights in 6 registers)
__global__ __launch_bounds__(256) void gemm1_kernel(
    const float* __restrict__ x,
    const float* __restrict__ W1l, const float* __restrict__ b1l,
    const float* __restrict__ W1r, const float* __restrict__ b1r,
    u16* __restrict__ xlr1)
{
    __shared__ float xs[32*INF];
    __shared__ float w[INF*256];
    __shared__ float bb[256];
    const int n0 = blockIdx.x*32, tid = threadIdx.x;
    for (int i = tid; i < INF*256; i += 256) {
        int k = i >> 8, j = i & 255;
        w[i] = (j < F1) ? W1l[k*F1 + j] : W1r[k*F1 + (j - F1)];
    }
    if (tid < 32*INF) xs[tid] = x[(size_t)n0*INF + tid];
    bb[tid] = (tid < F1) ? b1l[tid] : b1r[tid - F1];
    __syncthreads();
    const int j = tid;
    float wreg[INF];
    #pragma unroll
    for (int k = 0; k < INF; ++k) wreg[k] = w[k*256 + j];
    const float bv = bb[j];
    #pragma unroll 4
    for (int n = 0; n < 32; ++n) {
        float acc = bv;
        #pragma unroll
        for (int k = 0; k < INF; ++k) acc = fmaf(xs[n*INF + k], wreg[k], acc);
        xlr1[(size_t)(n0 + n)*256 + j] = f2b(acc);
    }
}

// ================= layer 1 attention + BN1 stats, one block/graph =================
// Structurally identical to gat2_attn with F1 dims; projections pre-computed in gemm1.
__global__ __launch_bounds__(256) void gat1_kernel(
    const u16* __restrict__ xlr1, const float* __restrict__ eattr,
    const float* __restrict__ We1, const float* __restrict__ att1,
    const float* __restrict__ bias1, float* __restrict__ h1,
    float* __restrict__ sum1, float* __restrict__ ss1)
{
    __shared__ float xl[PP*XR1];           // f32, [n][h*36 + c]
    __shared__ u32 xrp1[PP*XRR1];          // bf16 pairs, [n][h*20 + pair]
    __shared__ float ea[PP*PP];
    __shared__ float alpha[PP*4*ASX];
    __shared__ float2 wa1[4*HP1];
    const int g = blockIdx.x, tid = threadIdx.x;

    if (tid < F1) {
        int off = (tid >> 5)*HP1 + (tid & 31);
        wa1[off] = make_float2(We1[tid], att1[tid]);
    }
    for (int i4 = tid; i4 < PP*64; i4 += 256) {      // 18*256 elems in quads
        int n = i4 >> 6, jj = (i4 & 63)*4;
        const u16* src = &xlr1[(size_t)(g*PP + n)*256 + jj];
        if (jj < F1) {
            ushort4 v = *reinterpret_cast<const ushort4*>(src);
            int off = n*XR1 + (jj >> 5)*HP1 + (jj & 31);
            *(float4*)&xl[off] = make_float4(b2f(v.x), b2f(v.y), b2f(v.z), b2f(v.w));
        } else {
            uint2 p = *reinterpret_cast<const uint2*>(src);
            int j2 = jj - F1;
            int off = n*XRR1 + (j2 >> 5)*HPR1 + ((j2 & 31) >> 1);
            *(uint2*)&xrp1[off] = p;
        }
    }
    for (int t = tid; t < EPG; t += 256) {
        int s = t/17, pos = t%17;
        int d = pos + (pos >= s);
        ea[s*PP + d] = eattr[g*EPG + t];
    }
    __syncthreads();
    if (tid < PP) {
        float sum = 0.f;
        for (int s = 0; s < PP; ++s) if (s != tid) sum += ea[s*PP + tid];
        ea[tid*PP + tid] = sum * (1.f/17.f);
    }
    __syncthreads();
    // alpha: (fixed s, fixed h, 6 d); 8-c chunks; xl f32 b128, xr bf16-pair uint4
    {
        const int h = tid & 3, u = tid >> 2;
        const int s = u % PP, q = u / PP;
        if (q < 3) {
            const int d0 = q*6;
            const float* xlrow = &xl[s*XR1 + h*HP1];
            const u32*  xrb    = &xrp1[d0*XRR1 + h*HPR1];
            float e[6];
            #pragma unroll
            for (int dd = 0; dd < 6; ++dd) e[dd] = ea[s*PP + d0 + dd];
            float acc[6] = {0,0,0,0,0,0};
            #pragma unroll
            for (int ch = 0; ch < 4; ++ch) {
                const int cc = ch*8, cp = ch*4;
                float4 xla = *(const float4*)&xlrow[cc];
                float4 xlb = *(const float4*)&xlrow[cc + 4];
                float4 wa01 = *(const float4*)&wa1[h*HP1 + cc];
                float4 wa23 = *(const float4*)&wa1[h*HP1 + cc + 2];
                float4 wa45 = *(const float4*)&wa1[h*HP1 + cc + 4];
                float4 wa67 = *(const float4*)&wa1[h*HP1 + cc + 6];
                #pragma unroll
                for (int dd = 0; dd < 6; ++dd) {
                    uint4 xru = *(const uint4*)&xrb[dd*XRR1 + cp];
                    float ev = e[dd];
                    float v0 = fmaf(ev, wa01.x, xla.x + bpk_lo(xru.x)); v0 = fmaxf(v0, 0.01f*v0);
                    float v1 = fmaf(ev, wa01.z, xla.y + bpk_hi(xru.x)); v1 = fmaxf(v1, 0.01f*v1);
                    float v2 = fmaf(ev, wa23.x, xla.z + bpk_lo(xru.y)); v2 = fmaxf(v2, 0.01f*v2);
                    float v3 = fmaf(ev, wa23.z, xla.w + bpk_hi(xru.y)); v3 = fmaxf(v3, 0.01f*v3);
                    float v4 = fmaf(ev, wa45.x, xlb.x + bpk_lo(xru.z)); v4 = fmaxf(v4, 0.01f*v4);
                    float v5 = fmaf(ev, wa45.z, xlb.y + bpk_hi(xru.z)); v5 = fmaxf(v5, 0.01f*v5);
                    float v6 = fmaf(ev, wa67.x, xlb.z + bpk_lo(xru.w)); v6 = fmaxf(v6, 0.01f*v6);
                    float v7 = fmaf(ev, wa67.z, xlb.w + bpk_hi(xru.w)); v7 = fmaxf(v7, 0.01f*v7);
                    float a01 = fmaf(v0, wa01.y, v1*wa01.w);
                    float a23 = fmaf(v2, wa23.y, v3*wa23.w);
                    float a45 = fmaf(v4, wa45.y, v5*wa45.w);
                    float a67 = fmaf(v6, wa67.y, v7*wa67.w);
                    acc[dd] += (a01 + a23) + (a45 + a67);
                }
            }
            #pragma unroll
            for (int dd = 0; dd < 6; ++dd)
                alpha[((d0 + dd)*4 + h)*ASX + s] = acc[dd];
        }
    }
    __syncthreads();
    if (tid < PP*4) {
        float* a = &alpha[tid*ASX];
        float m = -1e30f;
        for (int s = 0; s < PP; ++s) m = fmaxf(m, a[s]);
        float sum = 0.f;
        for (int s = 0; s < PP; ++s) sum += __expf(a[s] - m);
        float inv = 1.f/(sum + 1e-16f);
        for (int s = 0; s < PP; ++s) a[s] = __expf(a[s] - m) * inv;
    }
    __syncthreads();
    // PV: thread owns column j = tid&127 (9 d's); xl column in registers
    float s_loc = 0.f, q_loc = 0.f;
    {
        const int j = tid & 127, h = j >> 5, c = j & 31, d0 = tid >> 7;
        float xlc[PP];
        #pragma unroll
        for (int s = 0; s < PP; ++s) xlc[s] = xl[s*XR1 + h*HP1 + c];
        const float bv = bias1[j];
        #pragma unroll
        for (int k = 0; k < 9; ++k) {
            int d = d0 + 2*k;
            const float* ap = &alpha[(d*4 + h)*ASX];
            float4 a0 = *(const float4*)&ap[0];
            float4 a1 = *(const float4*)&ap[4];
            float4 a2 = *(const float4*)&ap[8];
            float4 a3 = *(const float4*)&ap[12];
            float acc = bv;
            acc = fmaf(a0.x, xlc[0],  acc); acc = fmaf(a0.y, xlc[1],  acc);
            acc = fmaf(a0.z, xlc[2],  acc); acc = fmaf(a0.w, xlc[3],  acc);
            acc = fmaf(a1.x, xlc[4],  acc); acc = fmaf(a1.y, xlc[5],  acc);
            acc = fmaf(a1.z, xlc[6],  acc); acc = fmaf(a1.w, xlc[7],  acc);
            acc = fmaf(a2.x, xlc[8],  acc); acc = fmaf(a2.y, xlc[9],  acc);
            acc = fmaf(a2.z, xlc[10], acc); acc = fmaf(a2.w, xlc[11], acc);
            acc = fmaf(a3.x, xlc[12], acc); acc = fmaf(a3.y, xlc[13], acc);
            acc = fmaf(a3.z, xlc[14], acc); acc = fmaf(a3.w, xlc[15], acc);
            acc = fmaf(ap[16], xlc[16], acc); acc = fmaf(ap[17], xlc[17], acc);
            h1[(size_t)g*(PP*F1) + d*F1 + j] = acc;
            s_loc += acc;
            q_loc = fmaf(acc, acc, q_loc);
        }
    }
    atomicAdd(&sum1[tid & 127], s_loc);
    atomicAdd(&ss1[tid & 127], q_loc);
}

// ================= prep: W2 -> bf16 transposed, bias concat, zero stats =================
__global__ void prep_w(const float* __restrict__ W2l, const float* __restrict__ W2r,
                       const float* __restrict__ b2l, const float* __restrict__ b2r,
                       u16* __restrict__ wbt, float* __restrict__ biascat,
                       float* __restrict__ st)
{
    int t = blockIdx.x*blockDim.x + threadIdx.x;
    if (t < 1536) st[t] = 0.f;
    if (t < 512*128) {
        int c = t >> 7, k = t & 127;
        float v = (c < 256) ? W2l[k*256 + c] : W2r[k*256 + (c-256)];
        wbt[t] = f2b(v);           // wbt[c][k]
    } else if (t < 512*128 + 512) {
        int c = t - 512*128;
        biascat[c] = (c < 256) ? b2l[c] : b2r[c-256];
    }
}

// ================= layer-2 projection GEMM (bn1 finalize + lrelu fused into A-stage) ========
__global__ __launch_bounds__(256) void gemm2_kernel(
    const float* __restrict__ h1,
    const float* __restrict__ sum1, const float* __restrict__ ss1,
    const float* __restrict__ g1, const float* __restrict__ be1,
    const u16* __restrict__ wbt, const float* __restrict__ biascat, u16* __restrict__ xlr)
{
    __shared__ u16 As[64*128];
    __shared__ u16 Bs[64*128];
    __shared__ float scs[F1], shs[F1];
    const int b = blockIdx.x;
    const int bm = b >> 3, bn = b & 7;
    const int r0 = bm*64, c0 = bn*64;
    const int tid = threadIdx.x;

    if (tid < F1) {
        float mu = sum1[tid] * (1.f/NNODE);
        float var = ss1[tid] * (1.f/NNODE) - mu*mu;
        float s = g1[tid] * rsqrtf(var + 1e-5f);
        scs[tid] = s; shs[tid] = be1[tid] - mu*s;
    }
    __syncthreads();
    for (int i = tid*8; i < 64*128; i += 256*8) {
        int r = i >> 7, c = i & 127;
        float4 v0 = *(const float4*)&h1[(size_t)(r0+r)*128 + c];
        float4 v1 = *(const float4*)&h1[(size_t)(r0+r)*128 + c + 4];
        short8 a;
        a[0] = (short)f2b(lrelu(fmaf(scs[c+0], v0.x, shs[c+0])));
        a[1] = (short)f2b(lrelu(fmaf(scs[c+1], v0.y, shs[c+1])));
        a[2] = (short)f2b(lrelu(fmaf(scs[c+2], v0.z, shs[c+2])));
        a[3] = (short)f2b(lrelu(fmaf(scs[c+3], v0.w, shs[c+3])));
        a[4] = (short)f2b(lrelu(fmaf(scs[c+4], v1.x, shs[c+4])));
        a[5] = (short)f2b(lrelu(fmaf(scs[c+5], v1.y, shs[c+5])));
        a[6] = (short)f2b(lrelu(fmaf(scs[c+6], v1.z, shs[c+6])));
        a[7] = (short)f2b(lrelu(fmaf(scs[c+7], v1.w, shs[c+7])));
        int idx = i ^ ((r & 7) << 3);
        *reinterpret_cast<short8*>(&As[idx]) = a;
        *reinterpret_cast<short8*>(&Bs[idx]) =
            *reinterpret_cast<const short8*>(&wbt[(size_t)(c0+r)*128 + c]);
    }
    __syncthreads();

    const int w = tid >> 6, l = tid & 63;
    const int lr = l & 15, lk = (l >> 4) * 8;
    const int ar = w*16 + lr;
    f32x4 acc[4] = {f32x4{0,0,0,0}, f32x4{0,0,0,0}, f32x4{0,0,0,0}, f32x4{0,0,0,0}};

    #pragma unroll
    for (int kk = 0; kk < 4; ++kk) {
        int k0 = kk*32 + lk;
        short8 a = *reinterpret_cast<const short8*>(&As[(ar*128 + k0) ^ ((ar & 7) << 3)]);
        #pragma unroll
        for (int n = 0; n < 4; ++n) {
            int br = n*16 + lr;
            short8 bf = *reinterpret_cast<const short8*>(&Bs[(br*128 + k0) ^ ((br & 7) << 3)]);
            acc[n] = __builtin_amdgcn_mfma_f32_16x16x32_bf16(a, bf, acc[n], 0, 0, 0);
        }
    }
    const int rbase = r0 + w*16 + (l >> 4)*4;
    #pragma unroll
    for (int n = 0; n < 4; ++n) {
        int C = c0 + n*16 + lr;
        float bv = biascat[C];
        #pragma unroll
        for (int j = 0; j < 4; ++j) {
            xlr[(size_t)(rbase + j)*512 + C] = f2b(acc[n][j] + bv);
        }
    }
}

// ================= layer 2 attention + BN2 stats (R15-proven, unchanged) =================
__global__ __launch_bounds__(256) void gat2_attn(
    const u16* __restrict__ xlr, const float* __restrict__ eattr,
    const float* __restrict__ We2, const float* __restrict__ att2,
    const float* __restrict__ bias2, float* __restrict__ h2,
    float* __restrict__ sum2, float* __restrict__ ss2)
{
    __shared__ float xl[PP*XR2];
    __shared__ u32 xrp[PP*XRP];
    __shared__ float ea[PP*PP];
    __shared__ float alpha[PP*4*ASX];
    __shared__ float2 wa2[4*HP2];
    const int g = blockIdx.x, tid = threadIdx.x;

    {
        int off = (tid >> 6)*HP2 + (tid & 63);
        wa2[off] = make_float2(We2[tid], att2[tid]);
    }
    for (int i4 = tid; i4 < PP*128; i4 += 256) {
        int i = i4*4, n = i >> 9, j = i & 511;
        const u16* src = &xlr[(size_t)(g*PP + n)*512 + j];
        if (j < 256) {
            ushort4 v = *reinterpret_cast<const ushort4*>(src);
            int off = n*XR2 + (j >> 6)*HP2 + (j & 63);
            *(float4*)&xl[off] = make_float4(b2f(v.x), b2f(v.y), b2f(v.z), b2f(v.w));
        } else {
            uint2 p = *reinterpret_cast<const uint2*>(src);
            int j2 = j & 255;
            int off = n*XRP + (j2 >> 6)*HPP + ((j2 & 63) >> 1);
            *(uint2*)&xrp[off] = p;
        }
    }
    for (int t = tid; t < EPG; t += 256) {
        int s = t/17, pos = t%17;
        int d = pos + (pos >= s);
        ea[s*PP + d] = eattr[g*EPG + t];
    }
    __syncthreads();
    if (tid < PP) {
        float sum = 0.f;
        for (int s = 0; s < PP; ++s) if (s != tid) sum += ea[s*PP + tid];
        ea[tid*PP + tid] = sum * (1.f/17.f);
    }
    __syncthreads();
    {
        const int h = tid & 3, u = tid >> 2;
        const int s = u % PP, q = u / PP;
        if (q < 3) {
            const int d0 = q*6;
            const float* xlrow = &xl[s*XR2 + h*HP2];
            const u32*  xrb    = &xrp[d0*XRP + h*HPP];
            float e[6];
            #pragma unroll
            for (int dd = 0; dd < 6; ++dd) e[dd] = ea[s*PP + d0 + dd];
            float acc[6] = {0,0,0,0,0,0};
            #pragma unroll
            for (int ch = 0; ch < 8; ++ch) {
                const int cc = ch*8, cp = ch*4;
                float4 xla = *(const float4*)&xlrow[cc];
                float4 xlb = *(const float4*)&xlrow[cc + 4];
                float4 wa01 = *(const float4*)&wa2[h*HP2 + cc];
                float4 wa23 = *(const float4*)&wa2[h*HP2 + cc + 2];
                float4 wa45 = *(const float4*)&wa2[h*HP2 + cc + 4];
                float4 wa67 = *(const float4*)&wa2[h*HP2 + cc + 6];
                #pragma unroll
                for (int dd = 0; dd < 6; ++dd) {
                    uint4 xru = *(const uint4*)&xrb[dd*XRP + cp];
                    float ev = e[dd];
                    float v0 = fmaf(ev, wa01.x, xla.x + bpk_lo(xru.x)); v0 = fmaxf(v0, 0.01f*v0);
                    float v1 = fmaf(ev, wa01.z, xla.y + bpk_hi(xru.x)); v1 = fmaxf(v1, 0.01f*v1);
                    float v2 = fmaf(ev, wa23.x, xla.z + bpk_lo(xru.y)); v2 = fmaxf(v2, 0.01f*v2);
                    float v3 = fmaf(ev, wa23.z, xla.w + bpk_hi(xru.y)); v3 = fmaxf(v3, 0.01f*v3);
                    float v4 = fmaf(ev, wa45.x, xlb.x + bpk_lo(xru.z)); v4 = fmaxf(v4, 0.01f*v4);
                    float v5 = fmaf(ev, wa45.z, xlb.y + bpk_hi(xru.z)); v5 = fmaxf(v5, 0.01f*v5);
                    float v6 = fmaf(ev, wa67.x, xlb.z + bpk_lo(xru.w)); v6 = fmaxf(v6, 0.01f*v6);
                    float v7 = fmaf(ev, wa67.z, xlb.w + bpk_hi(xru.w)); v7 = fmaxf(v7, 0.01f*v7);
                    float a01 = fmaf(v0, wa01.y, v1*wa01.w);
                    float a23 = fmaf(v2, wa23.y, v3*wa23.w);
                    float a45 = fmaf(v4, wa45.y, v5*wa45.w);
                    float a67 = fmaf(v6, wa67.y, v7*wa67.w);
                    acc[dd] += (a01 + a23) + (a45 + a67);
                }
            }
            #pragma unroll
            for (int dd = 0; dd < 6; ++dd)
                alpha[((d0 + dd)*4 + h)*ASX + s] = acc[dd];
        }
    }
    __syncthreads();
    if (tid < PP*4) {
        float* a = &alpha[tid*ASX];
        float m = -1e30f;
        for (int s = 0; s < PP; ++s) m = fmaxf(m, a[s]);
        float sum = 0.f;
        for (int s = 0; s < PP; ++s) sum += __expf(a[s] - m);
        float inv = 1.f/(sum + 1e-16f);
        for (int s = 0; s < PP; ++s) a[s] = __expf(a[s] - m) * inv;
    }
    __syncthreads();
    float s_loc = 0.f, q_loc = 0.f;
    {
        const int j = tid, h = j >> 6, c = j & 63;
        float xlc[PP];
        #pragma unroll
        for (int s = 0; s < PP; ++s) xlc[s] = xl[s*XR2 + h*HP2 + c];
        const float bv = bias2[j];
        for (int d = 0; d < PP; ++d) {
            const float* ap = &alpha[(d*4 + h)*ASX];
            float4 a0 = *(const float4*)&ap[0];
            float4 a1 = *(const float4*)&ap[4];
            float4 a2 = *(const float4*)&ap[8];
            float4 a3 = *(const float4*)&ap[12];
            float acc = bv;
            acc = fmaf(a0.x, xlc[0],  acc); acc = fmaf(a0.y, xlc[1],  acc);
            acc = fmaf(a0.z, xlc[2],  acc); acc = fmaf(a0.w, xlc[3],  acc);
            acc = fmaf(a1.x, xlc[4],  acc); acc = fmaf(a1.y, xlc[5],  acc);
            acc = fmaf(a1.z, xlc[6],  acc); acc = fmaf(a1.w, xlc[7],  acc);
            acc = fmaf(a2.x, xlc[8],  acc); acc = fmaf(a2.y, xlc[9],  acc);
            acc = fmaf(a2.z, xlc[10], acc); acc = fmaf(a2.w, xlc[11], acc);
            acc = fmaf(a3.x, xlc[12], acc); acc = fmaf(a3.y, xlc[13], acc);
            acc = fmaf(a3.z, xlc[14], acc); acc = fmaf(a3.w, xlc[15], acc);
            acc = fmaf(ap[16], xlc[16], acc); acc = fmaf(ap[17], xlc[17], acc);
            h2[(size_t)g*(PP*F2) + d*F2 + j] = acc;
            s_loc += acc;
            q_loc = fmaf(acc, acc, q_loc);
        }
    }
    atomicAdd(&sum2[tid], s_loc);
    atomicAdd(&ss2[tid], q_loc);
}

// ===== BN2 finalize + lrelu + mean-pool + MLP head, 4 graphs/block, 512 threads, grid 512 =====
__global__ __launch_bounds__(512) void mlp_kernel(
    const float* __restrict__ h2,
    const float* __restrict__ sum2, const float* __restrict__ ss2,
    const float* __restrict__ g2, const float* __restrict__ be2,
    const float* __restrict__ Wfc1, const float* __restrict__ bfc1,
    const float* __restrict__ Wfc2, const float* __restrict__ bfc2,
    const float* __restrict__ Wfc3, const float* __restrict__ bfc3,
    float* __restrict__ out)
{
    __shared__ float pooled[4][F2];
    __shared__ float y1[4][512];
    __shared__ float part[3][4][128];
    __shared__ float y2[4][128];
    const int g0 = blockIdx.x * 4, tid = threadIdx.x;
    {
        const int col = tid & 255;
        float mu = sum2[col] * (1.f/NNODE);
        float var = ss2[col] * (1.f/NNODE) - mu*mu;
        const float scv = g2[col] * rsqrtf(var + 1e-5f);
        const float shv = be2[col] - mu*scv;
        #pragma unroll
        for (int r = 0; r < 2; ++r) {
            int gi = (tid >> 8) + 2*r;
            float s = 0.f;
            #pragma unroll 3
            for (int n = 0; n < PP; ++n) {
                float v = fmaf(scv, h2[((size_t)(g0+gi)*PP + n)*F2 + col], shv);
                s += fmaxf(v, 0.01f*v);
            }
            pooled[gi][col] = s * (1.f/18.f);
        }
    }
    __syncthreads();
    {
        const int j = tid;
        float acc[4];
        float bv = bfc1[j];
        #pragma unroll
        for (int gi = 0; gi < 4; ++gi) acc[gi] = bv;
        #pragma unroll 8
        for (int k = 0; k < F2; ++k) {
            float w = Wfc1[k*512 + j];
            #pragma unroll
            for (int gi = 0; gi < 4; ++gi) acc[gi] = fmaf(pooled[gi][k], w, acc[gi]);
        }
        #pragma unroll
        for (int gi = 0; gi < 4; ++gi) y1[gi][j] = fmaxf(acc[gi], 0.01f*acc[gi]);
    }
    __syncthreads();
    {
        const int kh = tid >> 7, j = tid & 127;
        float acc[4] = {0,0,0,0};
        #pragma unroll 8
        for (int k = kh*128; k < kh*128 + 128; ++k) {
            float w = Wfc2[k*128 + j];
            #pragma unroll
            for (int gi = 0; gi < 4; ++gi) acc[gi] = fmaf(y1[gi][k], w, acc[gi]);
        }
        if (kh > 0) {
            #pragma unroll
            for (int gi = 0; gi < 4; ++gi) part[kh-1][gi][j] = acc[gi];
        }
        __syncthreads();
        if (kh == 0) {
            float w3 = Wfc3[j], bv = bfc2[j];
            #pragma unroll
            for (int gi = 0; gi < 4; ++gi) {
                float v = acc[gi] + part[0][gi][j] + part[1][gi][j] + part[2][gi][j] + bv;
                y2[gi][j] = fmaxf(v, 0.01f*v) * w3;
            }
        }
    }
    __syncthreads();
    if (tid < 256) {
        int gi = tid >> 6, lx = tid & 63;
        float p = y2[gi][lx] + y2[gi][lx + 64];
        p += __shfl_xor(p, 1); p += __shfl_xor(p, 2); p += __shfl_xor(p, 4);
        p += __shfl_xor(p, 8); p += __shfl_xor(p, 16); p += __shfl_xor(p, 32);
        if (lx == 0) out[g0 + gi] = p + bfc3[0];
    }
}

extern "C" void kernel_launch(void* const* d_in, const int* in_sizes, int n_in,
                              void* d_out, int out_size, void* d_ws, size_t ws_size,
                              hipStream_t stream)
{
    const float* x     = (const float*)d_in[0];
    const float* eattr = (const float*)d_in[1];
    const float* W1l   = (const float*)d_in[4];
    const float* b1l   = (const float*)d_in[5];
    const float* W1r   = (const float*)d_in[6];
    const float* b1r   = (const float*)d_in[7];
    const float* We1   = (const float*)d_in[8];
    const float* att1  = (const float*)d_in[9];
    const float* bias1 = (const float*)d_in[10];
    const float* W2l   = (const float*)d_in[11];
    const float* b2l   = (const float*)d_in[12];
    const float* W2r   = (const float*)d_in[13];
    const float* b2r   = (const float*)d_in[14];
    const float* We2   = (const float*)d_in[15];
    const float* att2  = (const float*)d_in[16];
    const float* bias2 = (const float*)d_in[17];
    const float* g1    = (const float*)d_in[18];
    const float* be1   = (const float*)d_in[19];
    const float* g2    = (const float*)d_in[20];
    const float* be2   = (const float*)d_in[21];
    const float* Wfc1  = (const float*)d_in[22];
    const float* bfc1  = (const float*)d_in[23];
    const float* Wfc2  = (const float*)d_in[24];
    const float* bfc2  = (const float*)d_in[25];
    const float* Wfc3  = (const float*)d_in[26];
    const float* bfc3  = (const float*)d_in[27];
    float* out = (float*)d_out;

    float* ws = (float*)d_ws;
    float* h1 = ws;                                  // NNODE*128 f32
    float* h2 = h1 + (size_t)NNODE*F1;               // NNODE*256 f32
    float* st = h2 + (size_t)NNODE*F2;               // 1536 f32 stats
    float* biascat = st + 1536;                      // 512 f32
    u16* xlr = (u16*)(biascat + 512);                // NNODE*512 bf16
    u16* wbt = xlr + (size_t)NNODE*F2*2;             // 512*128 bf16
    u16* xlr1 = wbt + (size_t)512*128;               // NNODE*256 bf16

    float* sum1 = st,     *ss1 = st+128;
    float* sum2 = st+512, *ss2 = st+768;

    prep_w<<<259, 256, 0, stream>>>(W2l, W2r, b2l, b2r, wbt, biascat, st);
    gemm1_kernel<<<NNODE/32, 256, 0, stream>>>(x, W1l, b1l, W1r, b1r, xlr1);
    gat1_kernel<<<GG, 256, 0, stream>>>(xlr1, eattr, We1, att1, bias1, h1, sum1, ss1);
    gemm2_kernel<<<(NNODE/64)*8, 256, 0, stream>>>(h1, sum1, ss1, g1, be1, wbt, biascat, xlr);
    gat2_attn<<<GG, 256, 0, stream>>>(xlr, eattr, We2, att2, bias2, h2, sum2, ss2);
    mlp_kernel<<<GG/4, 512, 0, stream>>>(h2, sum2, ss2, g2, be2, Wfc1, bfc1, Wfc2, bfc2, Wfc3, bfc3, out);
}

// Round 18
// 203.427 us; speedup vs baseline: 1.2709x; 1.2709x over previous
//
#include <hip/hip_runtime.h>
#include <cstddef>

#define GG 2048
#define PP 18
#define NNODE (GG*PP)      // 36864
#define EPG 306            // directed edges per graph (17*18)
#define F1 128             // H1*C1
#define F2 256             // H2*C2
#define ASX 20             // alpha row stride: alpha[(d*4+h)*ASX + s]
#define INF 6
// gat1: xl f32 padded layout
#define HP1 36             // xl head stride (f32); also wa1 head stride (float2)
#define XR1 144            // xl row stride; mod 32 = 16
// gat1: xr bf16-PAIR layout (u32 units)
#define HPR1 20
#define XRR1 80            // mod 32 = 16
// gat2: xl f32 padded layout
#define HP2 68
#define XR2 272            // mod 32 = 16
// gat2: xr bf16-PAIR layout (u32 units)
#define HPP 36
#define XRP 144            // mod 32 = 16

typedef unsigned short u16;
typedef unsigned int u32;
typedef __attribute__((ext_vector_type(8))) short short8;   // 8 bf16
typedef __attribute__((ext_vector_type(4))) float f32x4;

__device__ __forceinline__ float lrelu(float v) { return fmaxf(v, 0.01f*v); }

__device__ __forceinline__ u16 f2b(float x) {            // fp32 -> bf16 RNE
    union { float f; unsigned u; } c; c.f = x;
    unsigned r = c.u + 0x7FFF + ((c.u >> 16) & 1);
    return (u16)(r >> 16);
}
__device__ __forceinline__ float b2f(u16 v) {
    union { unsigned u; float f; } c; c.u = ((unsigned)v) << 16;
    return c.f;
}
__device__ __forceinline__ float bpk_lo(u32 u) { return __uint_as_float(u << 16); }
__device__ __forceinline__ float bpk_hi(u32 u) { return __uint_as_float(u & 0xffff0000u); }

// ================= layer 1: GATv2 (6 -> 4x32) + BN1 stats, one block/graph =================
// R16 structure; projection hoists weight columns to registers (ILP fix).
__global__ __launch_bounds__(256) void gat1_kernel(
    const float* __restrict__ x, const float* __restrict__ eattr,
    const float* __restrict__ W1l, const float* __restrict__ b1l,
    const float* __restrict__ W1r, const float* __restrict__ b1r,
    const float* __restrict__ We1, const float* __restrict__ att1,
    const float* __restrict__ bias1, float* __restrict__ h1,
    float* __restrict__ sum1, float* __restrict__ ss1)
{
    __shared__ float xs[PP*INF];
    __shared__ float wl[INF*F1], wr[INF*F1];
    __shared__ float bl[F1], br[F1];
    __shared__ float2 wa1[4*HP1];
    __shared__ float ea[PP*PP];
    __shared__ float xl[PP*XR1];
    __shared__ u32 xrp1[PP*XRR1];          // bf16 pairs, [n][h*20 + pair]
    __shared__ float alpha[PP*4*ASX];
    const int g = blockIdx.x, tid = threadIdx.x;

    if (tid < PP*INF) xs[tid] = x[g*PP*INF + tid];
    for (int i = tid; i < INF*F1; i += 256) { wl[i] = W1l[i]; wr[i] = W1r[i]; }
    if (tid < F1) {
        bl[tid] = b1l[tid]; br[tid] = b1r[tid];
        int off = (tid >> 5)*HP1 + (tid & 31);
        wa1[off] = make_float2(We1[tid], att1[tid]);
    }
    for (int t = tid; t < EPG; t += 256) {
        int s = t/17, pos = t%17;
        int d = pos + (pos >= s);
        ea[s*PP + d] = eattr[g*EPG + t];
    }
    __syncthreads();
    if (tid < PP) {
        float sum = 0.f;
        for (int s = 0; s < PP; ++s) if (s != tid) sum += ea[s*PP + tid];
        ea[tid*PP + tid] = sum * (1.f/17.f);
    }
    __syncthreads();
    // projections: weight columns hoisted to registers; xl f32, xr bf16
    {
        const int j = tid & 127;
        float wlr[INF], wrr[INF];
        #pragma unroll
        for (int k = 0; k < INF; ++k) { wlr[k] = wl[k*F1 + j]; wrr[k] = wr[k*F1 + j]; }
        const float blv = bl[j], brv = br[j];
        u16* xr16 = (u16*)xrp1;
        const int xloff = (j >> 5)*HP1 + (j & 31);
        const int xroff = (j >> 5)*(2*HPR1) + (j & 31);
        for (int o = tid; o < PP*F1; o += 256) {
            int n = o >> 7;
            float al = blv, ar = brv;
            #pragma unroll
            for (int k = 0; k < INF; ++k) {
                float xv = xs[n*INF + k];
                al = fmaf(xv, wlr[k], al);
                ar = fmaf(xv, wrr[k], ar);
            }
            xl[n*XR1 + xloff] = al;
            xr16[n*(2*XRR1) + xroff] = f2b(ar);
        }
    }
    __syncthreads();
    // alpha: (fixed s, fixed h, 6 d); 8-c chunks; xl f32 b128, xr bf16-pair uint4
    {
        const int h = tid & 3, u = tid >> 2;
        const int s = u % PP, q = u / PP;
        if (q < 3) {
            const int d0 = q*6;
            const float* xlrow = &xl[s*XR1 + h*HP1];
            const u32*  xrb    = &xrp1[d0*XRR1 + h*HPR1];
            float e[6];
            #pragma unroll
            for (int dd = 0; dd < 6; ++dd) e[dd] = ea[s*PP + d0 + dd];
            float acc[6] = {0,0,0,0,0,0};
            #pragma unroll
            for (int ch = 0; ch < 4; ++ch) {           // 8 c per chunk
                const int cc = ch*8, cp = ch*4;
                float4 xla = *(const float4*)&xlrow[cc];
                float4 xlb = *(const float4*)&xlrow[cc + 4];
                float4 wa01 = *(const float4*)&wa1[h*HP1 + cc];
                float4 wa23 = *(const float4*)&wa1[h*HP1 + cc + 2];
                float4 wa45 = *(const float4*)&wa1[h*HP1 + cc + 4];
                float4 wa67 = *(const float4*)&wa1[h*HP1 + cc + 6];
                #pragma unroll
                for (int dd = 0; dd < 6; ++dd) {
                    uint4 xru = *(const uint4*)&xrb[dd*XRR1 + cp];
                    float ev = e[dd];
                    float v0 = fmaf(ev, wa01.x, xla.x + bpk_lo(xru.x)); v0 = fmaxf(v0, 0.01f*v0);
                    float v1 = fmaf(ev, wa01.z, xla.y + bpk_hi(xru.x)); v1 = fmaxf(v1, 0.01f*v1);
                    float v2 = fmaf(ev, wa23.x, xla.z + bpk_lo(xru.y)); v2 = fmaxf(v2, 0.01f*v2);
                    float v3 = fmaf(ev, wa23.z, xla.w + bpk_hi(xru.y)); v3 = fmaxf(v3, 0.01f*v3);
                    float v4 = fmaf(ev, wa45.x, xlb.x + bpk_lo(xru.z)); v4 = fmaxf(v4, 0.01f*v4);
                    float v5 = fmaf(ev, wa45.z, xlb.y + bpk_hi(xru.z)); v5 = fmaxf(v5, 0.01f*v5);
                    float v6 = fmaf(ev, wa67.x, xlb.z + bpk_lo(xru.w)); v6 = fmaxf(v6, 0.01f*v6);
                    float v7 = fmaf(ev, wa67.z, xlb.w + bpk_hi(xru.w)); v7 = fmaxf(v7, 0.01f*v7);
                    float a01 = fmaf(v0, wa01.y, v1*wa01.w);
                    float a23 = fmaf(v2, wa23.y, v3*wa23.w);
                    float a45 = fmaf(v4, wa45.y, v5*wa45.w);
                    float a67 = fmaf(v6, wa67.y, v7*wa67.w);
                    acc[dd] += (a01 + a23) + (a45 + a67);
                }
            }
            #pragma unroll
            for (int dd = 0; dd < 6; ++dd)
                alpha[((d0 + dd)*4 + h)*ASX + s] = acc[dd];
        }
    }
    __syncthreads();
    if (tid < PP*4) {
        float* a = &alpha[tid*ASX];
        float m = -1e30f;
        for (int s = 0; s < PP; ++s) m = fmaxf(m, a[s]);
        float sum = 0.f;
        for (int s = 0; s < PP; ++s) sum += __expf(a[s] - m);
        float inv = 1.f/(sum + 1e-16f);
        for (int s = 0; s < PP; ++s) a[s] = __expf(a[s] - m) * inv;
    }
    __syncthreads();
    float s_loc = 0.f, q_loc = 0.f;
    {
        const int j = tid & 127, h = j >> 5, c = j & 31, d0 = tid >> 7;
        float xlc[PP];
        #pragma unroll
        for (int s = 0; s < PP; ++s) xlc[s] = xl[s*XR1 + h*HP1 + c];
        const float bv = bias1[j];
        #pragma unroll
        for (int k = 0; k < 9; ++k) {
            int d = d0 + 2*k;
            const float* ap = &alpha[(d*4 + h)*ASX];
            float4 a0 = *(const float4*)&ap[0];
            float4 a1 = *(const float4*)&ap[4];
            float4 a2 = *(const float4*)&ap[8];
            float4 a3 = *(const float4*)&ap[12];
            float acc = bv;
            acc = fmaf(a0.x, xlc[0],  acc); acc = fmaf(a0.y, xlc[1],  acc);
            acc = fmaf(a0.z, xlc[2],  acc); acc = fmaf(a0.w, xlc[3],  acc);
            acc = fmaf(a1.x, xlc[4],  acc); acc = fmaf(a1.y, xlc[5],  acc);
            acc = fmaf(a1.z, xlc[6],  acc); acc = fmaf(a1.w, xlc[7],  acc);
            acc = fmaf(a2.x, xlc[8],  acc); acc = fmaf(a2.y, xlc[9],  acc);
            acc = fmaf(a2.z, xlc[10], acc); acc = fmaf(a2.w, xlc[11], acc);
            acc = fmaf(a3.x, xlc[12], acc); acc = fmaf(a3.y, xlc[13], acc);
            acc = fmaf(a3.z, xlc[14], acc); acc = fmaf(a3.w, xlc[15], acc);
            acc = fmaf(ap[16], xlc[16], acc); acc = fmaf(ap[17], xlc[17], acc);
            h1[(size_t)g*(PP*F1) + d*F1 + j] = acc;
            s_loc += acc;
            q_loc = fmaf(acc, acc, q_loc);
        }
    }
    __syncthreads();
    wl[tid] = s_loc;
    wr[tid] = q_loc;
    __syncthreads();
    if (tid < F1) {
        atomicAdd(&sum1[tid], wl[tid] + wl[tid + 128]);
        atomicAdd(&ss1[tid],  wr[tid] + wr[tid + 128]);
    }
}

// ================= prep: W2 -> bf16 transposed, bias concat, zero stats =================
__global__ void prep_w(const float* __restrict__ W2l, const float* __restrict__ W2r,
                       const float* __restrict__ b2l, const float* __restrict__ b2r,
                       u16* __restrict__ wbt, float* __restrict__ biascat,
                       float* __restrict__ st)
{
    int t = blockIdx.x*blockDim.x + threadIdx.x;
    if (t < 1536) st[t] = 0.f;
    if (t < 512*128) {
        int c = t >> 7, k = t & 127;
        float v = (c < 256) ? W2l[k*256 + c] : W2r[k*256 + (c-256)];
        wbt[t] = f2b(v);           // wbt[c][k]
    } else if (t < 512*128 + 512) {
        int c = t - 512*128;
        biascat[c] = (c < 256) ? b2l[c] : b2r[c-256];
    }
}

// ================= layer-2 projection GEMM (bn1 finalize + lrelu fused into A-stage) ========
__global__ __launch_bounds__(256) void gemm2_kernel(
    const float* __restrict__ h1,
    const float* __restrict__ sum1, const float* __restrict__ ss1,
    const float* __restrict__ g1, const float* __restrict__ be1,
    const u16* __restrict__ wbt, const float* __restrict__ biascat, u16* __restrict__ xlr)
{
    __shared__ u16 As[64*128];
    __shared__ u16 Bs[64*128];
    __shared__ float scs[F1], shs[F1];
    const int b = blockIdx.x;
    const int bm = b >> 3, bn = b & 7;
    const int r0 = bm*64, c0 = bn*64;
    const int tid = threadIdx.x;

    if (tid < F1) {
        float mu = sum1[tid] * (1.f/NNODE);
        float var = ss1[tid] * (1.f/NNODE) - mu*mu;
        float s = g1[tid] * rsqrtf(var + 1e-5f);
        scs[tid] = s; shs[tid] = be1[tid] - mu*s;
    }
    __syncthreads();
    for (int i = tid*8; i < 64*128; i += 256*8) {
        int r = i >> 7, c = i & 127;
        float4 v0 = *(const float4*)&h1[(size_t)(r0+r)*128 + c];
        float4 v1 = *(const float4*)&h1[(size_t)(r0+r)*128 + c + 4];
        short8 a;
        a[0] = (short)f2b(lrelu(fmaf(scs[c+0], v0.x, shs[c+0])));
        a[1] = (short)f2b(lrelu(fmaf(scs[c+1], v0.y, shs[c+1])));
        a[2] = (short)f2b(lrelu(fmaf(scs[c+2], v0.z, shs[c+2])));
        a[3] = (short)f2b(lrelu(fmaf(scs[c+3], v0.w, shs[c+3])));
        a[4] = (short)f2b(lrelu(fmaf(scs[c+4], v1.x, shs[c+4])));
        a[5] = (short)f2b(lrelu(fmaf(scs[c+5], v1.y, shs[c+5])));
        a[6] = (short)f2b(lrelu(fmaf(scs[c+6], v1.z, shs[c+6])));
        a[7] = (short)f2b(lrelu(fmaf(scs[c+7], v1.w, shs[c+7])));
        int idx = i ^ ((r & 7) << 3);
        *reinterpret_cast<short8*>(&As[idx]) = a;
        *reinterpret_cast<short8*>(&Bs[idx]) =
            *reinterpret_cast<const short8*>(&wbt[(size_t)(c0+r)*128 + c]);
    }
    __syncthreads();

    const int w = tid >> 6, l = tid & 63;
    const int lr = l & 15, lk = (l >> 4) * 8;
    const int ar = w*16 + lr;
    f32x4 acc[4] = {f32x4{0,0,0,0}, f32x4{0,0,0,0}, f32x4{0,0,0,0}, f32x4{0,0,0,0}};

    #pragma unroll
    for (int kk = 0; kk < 4; ++kk) {
        int k0 = kk*32 + lk;
        short8 a = *reinterpret_cast<const short8*>(&As[(ar*128 + k0) ^ ((ar & 7) << 3)]);
        #pragma unroll
        for (int n = 0; n < 4; ++n) {
            int br = n*16 + lr;
            short8 bf = *reinterpret_cast<const short8*>(&Bs[(br*128 + k0) ^ ((br & 7) << 3)]);
            acc[n] = __builtin_amdgcn_mfma_f32_16x16x32_bf16(a, bf, acc[n], 0, 0, 0);
        }
    }
    const int rbase = r0 + w*16 + (l >> 4)*4;
    #pragma unroll
    for (int n = 0; n < 4; ++n) {
        int C = c0 + n*16 + lr;
        float bv = biascat[C];
        #pragma unroll
        for (int j = 0; j < 4; ++j) {
            xlr[(size_t)(rbase + j)*512 + C] = f2b(acc[n][j] + bv);
        }
    }
}

// ================= layer 2 attention + BN2 stats (R15-proven, unchanged) =================
__global__ __launch_bounds__(256) void gat2_attn(
    const u16* __restrict__ xlr, const float* __restrict__ eattr,
    const float* __restrict__ We2, const float* __restrict__ att2,
    const float* __restrict__ bias2, float* __restrict__ h2,
    float* __restrict__ sum2, float* __restrict__ ss2)
{
    __shared__ float xl[PP*XR2];
    __shared__ u32 xrp[PP*XRP];
    __shared__ float ea[PP*PP];
    __shared__ float alpha[PP*4*ASX];
    __shared__ float2 wa2[4*HP2];
    const int g = blockIdx.x, tid = threadIdx.x;

    {
        int off = (tid >> 6)*HP2 + (tid & 63);
        wa2[off] = make_float2(We2[tid], att2[tid]);
    }
    for (int i4 = tid; i4 < PP*128; i4 += 256) {
        int i = i4*4, n = i >> 9, j = i & 511;
        const u16* src = &xlr[(size_t)(g*PP + n)*512 + j];
        if (j < 256) {
            ushort4 v = *reinterpret_cast<const ushort4*>(src);
            int off = n*XR2 + (j >> 6)*HP2 + (j & 63);
            *(float4*)&xl[off] = make_float4(b2f(v.x), b2f(v.y), b2f(v.z), b2f(v.w));
        } else {
            uint2 p = *reinterpret_cast<const uint2*>(src);
            int j2 = j & 255;
            int off = n*XRP + (j2 >> 6)*HPP + ((j2 & 63) >> 1);
            *(uint2*)&xrp[off] = p;
        }
    }
    for (int t = tid; t < EPG; t += 256) {
        int s = t/17, pos = t%17;
        int d = pos + (pos >= s);
        ea[s*PP + d] = eattr[g*EPG + t];
    }
    __syncthreads();
    if (tid < PP) {
        float sum = 0.f;
        for (int s = 0; s < PP; ++s) if (s != tid) sum += ea[s*PP + tid];
        ea[tid*PP + tid] = sum * (1.f/17.f);
    }
    __syncthreads();
    {
        const int h = tid & 3, u = tid >> 2;
        const int s = u % PP, q = u / PP;
        if (q < 3) {
            const int d0 = q*6;
            const float* xlrow = &xl[s*XR2 + h*HP2];
            const u32*  xrb    = &xrp[d0*XRP + h*HPP];
            float e[6];
            #pragma unroll
            for (int dd = 0; dd < 6; ++dd) e[dd] = ea[s*PP + d0 + dd];
            float acc[6] = {0,0,0,0,0,0};
            #pragma unroll
            for (int ch = 0; ch < 8; ++ch) {
                const int cc = ch*8, cp = ch*4;
                float4 xla = *(const float4*)&xlrow[cc];
                float4 xlb = *(const float4*)&xlrow[cc + 4];
                float4 wa01 = *(const float4*)&wa2[h*HP2 + cc];
                float4 wa23 = *(const float4*)&wa2[h*HP2 + cc + 2];
                float4 wa45 = *(const float4*)&wa2[h*HP2 + cc + 4];
                float4 wa67 = *(const float4*)&wa2[h*HP2 + cc + 6];
                #pragma unroll
                for (int dd = 0; dd < 6; ++dd) {
                    uint4 xru = *(const uint4*)&xrb[dd*XRP + cp];
                    float ev = e[dd];
                    float v0 = fmaf(ev, wa01.x, xla.x + bpk_lo(xru.x)); v0 = fmaxf(v0, 0.01f*v0);
                    float v1 = fmaf(ev, wa01.z, xla.y + bpk_hi(xru.x)); v1 = fmaxf(v1, 0.01f*v1);
                    float v2 = fmaf(ev, wa23.x, xla.z + bpk_lo(xru.y)); v2 = fmaxf(v2, 0.01f*v2);
                    float v3 = fmaf(ev, wa23.z, xla.w + bpk_hi(xru.y)); v3 = fmaxf(v3, 0.01f*v3);
                    float v4 = fmaf(ev, wa45.x, xlb.x + bpk_lo(xru.z)); v4 = fmaxf(v4, 0.01f*v4);
                    float v5 = fmaf(ev, wa45.z, xlb.y + bpk_hi(xru.z)); v5 = fmaxf(v5, 0.01f*v5);
                    float v6 = fmaf(ev, wa67.x, xlb.z + bpk_lo(xru.w)); v6 = fmaxf(v6, 0.01f*v6);
                    float v7 = fmaf(ev, wa67.z, xlb.w + bpk_hi(xru.w)); v7 = fmaxf(v7, 0.01f*v7);
                    float a01 = fmaf(v0, wa01.y, v1*wa01.w);
                    float a23 = fmaf(v2, wa23.y, v3*wa23.w);
                    float a45 = fmaf(v4, wa45.y, v5*wa45.w);
                    float a67 = fmaf(v6, wa67.y, v7*wa67.w);
                    acc[dd] += (a01 + a23) + (a45 + a67);
                }
            }
            #pragma unroll
            for (int dd = 0; dd < 6; ++dd)
                alpha[((d0 + dd)*4 + h)*ASX + s] = acc[dd];
        }
    }
    __syncthreads();
    if (tid < PP*4) {
        float* a = &alpha[tid*ASX];
        float m = -1e30f;
        for (int s = 0; s < PP; ++s) m = fmaxf(m, a[s]);
        float sum = 0.f;
        for (int s = 0; s < PP; ++s) sum += __expf(a[s] - m);
        float inv = 1.f/(sum + 1e-16f);
        for (int s = 0; s < PP; ++s) a[s] = __expf(a[s] - m) * inv;
    }
    __syncthreads();
    float s_loc = 0.f, q_loc = 0.f;
    {
        const int j = tid, h = j >> 6, c = j & 63;
        float xlc[PP];
        #pragma unroll
        for (int s = 0; s < PP; ++s) xlc[s] = xl[s*XR2 + h*HP2 + c];
        const float bv = bias2[j];
        for (int d = 0; d < PP; ++d) {
            const float* ap = &alpha[(d*4 + h)*ASX];
            float4 a0 = *(const float4*)&ap[0];
            float4 a1 = *(const float4*)&ap[4];
            float4 a2 = *(const float4*)&ap[8];
            float4 a3 = *(const float4*)&ap[12];
            float acc = bv;
            acc = fmaf(a0.x, xlc[0],  acc); acc = fmaf(a0.y, xlc[1],  acc);
            acc = fmaf(a0.z, xlc[2],  acc); acc = fmaf(a0.w, xlc[3],  acc);
            acc = fmaf(a1.x, xlc[4],  acc); acc = fmaf(a1.y, xlc[5],  acc);
            acc = fmaf(a1.z, xlc[6],  acc); acc = fmaf(a1.w, xlc[7],  acc);
            acc = fmaf(a2.x, xlc[8],  acc); acc = fmaf(a2.y, xlc[9],  acc);
            acc = fmaf(a2.z, xlc[10], acc); acc = fmaf(a2.w, xlc[11], acc);
            acc = fmaf(a3.x, xlc[12], acc); acc = fmaf(a3.y, xlc[13], acc);
            acc = fmaf(a3.z, xlc[14], acc); acc = fmaf(a3.w, xlc[15], acc);
            acc = fmaf(ap[16], xlc[16], acc); acc = fmaf(ap[17], xlc[17], acc);
            h2[(size_t)g*(PP*F2) + d*F2 + j] = acc;
            s_loc += acc;
            q_loc = fmaf(acc, acc, q_loc);
        }
    }
    atomicAdd(&sum2[tid], s_loc);
    atomicAdd(&ss2[tid], q_loc);
}

// ===== BN2 finalize + lrelu + mean-pool + MLP head, 4 graphs/block, 512 threads, grid 512 =====
__global__ __launch_bounds__(512) void mlp_kernel(
    const float* __restrict__ h2,
    const float* __restrict__ sum2, const float* __restrict__ ss2,
    const float* __restrict__ g2, const float* __restrict__ be2,
    const float* __restrict__ Wfc1, const float* __restrict__ bfc1,
    const float* __restrict__ Wfc2, const float* __restrict__ bfc2,
    const float* __restrict__ Wfc3, const float* __restrict__ bfc3,
    float* __restrict__ out)
{
    __shared__ float pooled[4][F2];
    __shared__ float y1[4][512];
    __shared__ float part[3][4][128];
    __shared__ float y2[4][128];
    const int g0 = blockIdx.x * 4, tid = threadIdx.x;
    {
        const int col = tid & 255;
        float mu = sum2[col] * (1.f/NNODE);
        float var = ss2[col] * (1.f/NNODE) - mu*mu;
        const float scv = g2[col] * rsqrtf(var + 1e-5f);
        const float shv = be2[col] - mu*scv;
        #pragma unroll
        for (int r = 0; r < 2; ++r) {
            int gi = (tid >> 8) + 2*r;
            float s = 0.f;
            #pragma unroll 3
            for (int n = 0; n < PP; ++n) {
                float v = fmaf(scv, h2[((size_t)(g0+gi)*PP + n)*F2 + col], shv);
                s += fmaxf(v, 0.01f*v);
            }
            pooled[gi][col] = s * (1.f/18.f);
        }
    }
    __syncthreads();
    {
        const int j = tid;
        float acc[4];
        float bv = bfc1[j];
        #pragma unroll
        for (int gi = 0; gi < 4; ++gi) acc[gi] = bv;
        #pragma unroll 8
        for (int k = 0; k < F2; ++k) {
            float w = Wfc1[k*512 + j];
            #pragma unroll
            for (int gi = 0; gi < 4; ++gi) acc[gi] = fmaf(pooled[gi][k], w, acc[gi]);
        }
        #pragma unroll
        for (int gi = 0; gi < 4; ++gi) y1[gi][j] = fmaxf(acc[gi], 0.01f*acc[gi]);
    }
    __syncthreads();
    {
        const int kh = tid >> 7, j = tid & 127;
        float acc[4] = {0,0,0,0};
        #pragma unroll 8
        for (int k = kh*128; k < kh*128 + 128; ++k) {
            float w = Wfc2[k*128 + j];
            #pragma unroll
            for (int gi = 0; gi < 4; ++gi) acc[gi] = fmaf(y1[gi][k], w, acc[gi]);
        }
        if (kh > 0) {
            #pragma unroll
            for (int gi = 0; gi < 4; ++gi) part[kh-1][gi][j] = acc[gi];
        }
        __syncthreads();
        if (kh == 0) {
            float w3 = Wfc3[j], bv = bfc2[j];
            #pragma unroll
            for (int gi = 0; gi < 4; ++gi) {
                float v = acc[gi] + part[0][gi][j] + part[1][gi][j] + part[2][gi][j] + bv;
                y2[gi][j] = fmaxf(v, 0.01f*v) * w3;
            }
        }
    }
    __syncthreads();
    if (tid < 256) {
        int gi = tid >> 6, lx = tid & 63;
        float p = y2[gi][lx] + y2[gi][lx + 64];
        p += __shfl_xor(p, 1); p += __shfl_xor(p, 2); p += __shfl_xor(p, 4);
        p += __shfl_xor(p, 8); p += __shfl_xor(p, 16); p += __shfl_xor(p, 32);
        if (lx == 0) out[g0 + gi] = p + bfc3[0];
    }
}

extern "C" void kernel_launch(void* const* d_in, const int* in_sizes, int n_in,
                              void* d_out, int out_size, void* d_ws, size_t ws_size,
                              hipStream_t stream)
{
    const float* x     = (const float*)d_in[0];
    const float* eattr = (const float*)d_in[1];
    const float* W1l   = (const float*)d_in[4];
    const float* b1l   = (const float*)d_in[5];
    const float* W1r   = (const float*)d_in[6];
    const float* b1r   = (const float*)d_in[7];
    const float* We1   = (const float*)d_in[8];
    const float* att1  = (const float*)d_in[9];
    const float* bias1 = (const float*)d_in[10];
    const float* W2l   = (const float*)d_in[11];
    const float* b2l   = (const float*)d_in[12];
    const float* W2r   = (const float*)d_in[13];
    const float* b2r   = (const float*)d_in[14];
    const float* We2   = (const float*)d_in[15];
    const float* att2  = (const float*)d_in[16];
    const float* bias2 = (const float*)d_in[17];
    const float* g1    = (const float*)d_in[18];
    const float* be1   = (const float*)d_in[19];
    const float* g2    = (const float*)d_in[20];
    const float* be2   = (const float*)d_in[21];
    const float* Wfc1  = (const float*)d_in[22];
    const float* bfc1  = (const float*)d_in[23];
    const float* Wfc2  = (const float*)d_in[24];
    const float* bfc2  = (const float*)d_in[25];
    const float* Wfc3  = (const float*)d_in[26];
    const float* bfc3  = (const float*)d_in[27];
    float* out = (float*)d_out;

    float* ws = (float*)d_ws;
    float* h1 = ws;                                  // NNODE*128 f32
    float* h2 = h1 + (size_t)NNODE*F1;               // NNODE*256 f32
    float* st = h2 + (size_t)NNODE*F2;               // 1536 f32 stats
    float* biascat = st + 1536;                      // 512 f32
    u16* xlr = (u16*)(biascat + 512);                // NNODE*512 bf16
    u16* wbt = xlr + (size_t)NNODE*F2*2;             // 512*128 bf16

    float* sum1 = st,     *ss1 = st+128;
    float* sum2 = st+512, *ss2 = st+768;

    prep_w<<<259, 256, 0, stream>>>(W2l, W2r, b2l, b2r, wbt, biascat, st);
    gat1_kernel<<<GG, 256, 0, stream>>>(x, eattr, W1l, b1l, W1r, b1r, We1, att1, bias1, h1, sum1, ss1);
    gemm2_kernel<<<(NNODE/64)*8, 256, 0, stream>>>(h1, sum1, ss1, g1, be1, wbt, biascat, xlr);
    gat2_attn<<<GG, 256, 0, stream>>>(xlr, eattr, We2, att2, bias2, h2, sum2, ss2);
    mlp_kernel<<<GG/4, 512, 0, stream>>>(h2, sum2, ss2, g2, be2, Wfc1, bfc1, Wfc2, bfc2, Wfc3, bfc3, out);
}

// Round 19
// 195.116 us; speedup vs baseline: 1.3251x; 1.0426x over previous
//
#include <hip/hip_runtime.h>
#include <cstddef>

#define GG 2048
#define PP 18
#define NNODE (GG*PP)      // 36864
#define EPG 306            // directed edges per graph (17*18)
#define F1 128             // H1*C1
#define F2 256             // H2*C2
#define ASX 20             // alpha row stride: alpha[(d*4+h)*ASX + s]
#define INF 6
// gat1: xl f32 padded layout
#define HP1 36             // xl head stride (f32); also wa1 head stride (float2)
#define XR1 144            // xl row stride; mod 32 = 16
// gat1: xr bf16-PAIR layout (u32 units)
#define HPR1 20
#define XRR1 80            // mod 32 = 16
// gat2: xl f32 padded layout
#define HP2 68
#define XR2 272            // mod 32 = 16
// gat2: xr bf16-PAIR layout (u32 units)
#define HPP 36
#define XRP 144            // mod 32 = 16

typedef unsigned short u16;
typedef unsigned int u32;
typedef __attribute__((ext_vector_type(8))) short short8;   // 8 bf16
typedef __attribute__((ext_vector_type(4))) float f32x4;

__device__ __forceinline__ float lrelu(float v) { return fmaxf(v, 0.01f*v); }

__device__ __forceinline__ u16 f2b(float x) {            // fp32 -> bf16 RNE
    union { float f; unsigned u; } c; c.f = x;
    unsigned r = c.u + 0x7FFF + ((c.u >> 16) & 1);
    return (u16)(r >> 16);
}
__device__ __forceinline__ float b2f(u16 v) {
    union { unsigned u; float f; } c; c.u = ((unsigned)v) << 16;
    return c.f;
}
__device__ __forceinline__ float bpk_lo(u32 u) { return __uint_as_float(u << 16); }
__device__ __forceinline__ float bpk_hi(u32 u) { return __uint_as_float(u & 0xffff0000u); }

// ================= layer 1: GATv2 (6 -> 4x32) + BN1 stats, one block/graph =================
// R18 structure; h1 output stored as bf16 (halves h1 HBM round-trip).
__global__ __launch_bounds__(256) void gat1_kernel(
    const float* __restrict__ x, const float* __restrict__ eattr,
    const float* __restrict__ W1l, const float* __restrict__ b1l,
    const float* __restrict__ W1r, const float* __restrict__ b1r,
    const float* __restrict__ We1, const float* __restrict__ att1,
    const float* __restrict__ bias1, u16* __restrict__ h1b,
    float* __restrict__ sum1, float* __restrict__ ss1)
{
    __shared__ float xs[PP*INF];
    __shared__ float wl[INF*F1], wr[INF*F1];
    __shared__ float bl[F1], br[F1];
    __shared__ float2 wa1[4*HP1];
    __shared__ float ea[PP*PP];
    __shared__ float xl[PP*XR1];
    __shared__ u32 xrp1[PP*XRR1];          // bf16 pairs, [n][h*20 + pair]
    __shared__ float alpha[PP*4*ASX];
    const int g = blockIdx.x, tid = threadIdx.x;

    if (tid < PP*INF) xs[tid] = x[g*PP*INF + tid];
    for (int i = tid; i < INF*F1; i += 256) { wl[i] = W1l[i]; wr[i] = W1r[i]; }
    if (tid < F1) {
        bl[tid] = b1l[tid]; br[tid] = b1r[tid];
        int off = (tid >> 5)*HP1 + (tid & 31);
        wa1[off] = make_float2(We1[tid], att1[tid]);
    }
    for (int t = tid; t < EPG; t += 256) {
        int s = t/17, pos = t%17;
        int d = pos + (pos >= s);
        ea[s*PP + d] = eattr[g*EPG + t];
    }
    __syncthreads();
    if (tid < PP) {
        float sum = 0.f;
        for (int s = 0; s < PP; ++s) if (s != tid) sum += ea[s*PP + tid];
        ea[tid*PP + tid] = sum * (1.f/17.f);
    }
    __syncthreads();
    // projections: weight columns hoisted to registers; xl f32, xr bf16
    {
        const int j = tid & 127;
        float wlr[INF], wrr[INF];
        #pragma unroll
        for (int k = 0; k < INF; ++k) { wlr[k] = wl[k*F1 + j]; wrr[k] = wr[k*F1 + j]; }
        const float blv = bl[j], brv = br[j];
        u16* xr16 = (u16*)xrp1;
        const int xloff = (j >> 5)*HP1 + (j & 31);
        const int xroff = (j >> 5)*(2*HPR1) + (j & 31);
        for (int o = tid; o < PP*F1; o += 256) {
            int n = o >> 7;
            float al = blv, ar = brv;
            #pragma unroll
            for (int k = 0; k < INF; ++k) {
                float xv = xs[n*INF + k];
                al = fmaf(xv, wlr[k], al);
                ar = fmaf(xv, wrr[k], ar);
            }
            xl[n*XR1 + xloff] = al;
            xr16[n*(2*XRR1) + xroff] = f2b(ar);
        }
    }
    __syncthreads();
    // alpha: (fixed s, fixed h, 6 d); 8-c chunks; xl f32 b128, xr bf16-pair uint4
    {
        const int h = tid & 3, u = tid >> 2;
        const int s = u % PP, q = u / PP;
        if (q < 3) {
            const int d0 = q*6;
            const float* xlrow = &xl[s*XR1 + h*HP1];
            const u32*  xrb    = &xrp1[d0*XRR1 + h*HPR1];
            float e[6];
            #pragma unroll
            for (int dd = 0; dd < 6; ++dd) e[dd] = ea[s*PP + d0 + dd];
            float acc[6] = {0,0,0,0,0,0};
            #pragma unroll
            for (int ch = 0; ch < 4; ++ch) {           // 8 c per chunk
                const int cc = ch*8, cp = ch*4;
                float4 xla = *(const float4*)&xlrow[cc];
                float4 xlb = *(const float4*)&xlrow[cc + 4];
                float4 wa01 = *(const float4*)&wa1[h*HP1 + cc];
                float4 wa23 = *(const float4*)&wa1[h*HP1 + cc + 2];
                float4 wa45 = *(const float4*)&wa1[h*HP1 + cc + 4];
                float4 wa67 = *(const float4*)&wa1[h*HP1 + cc + 6];
                #pragma unroll
                for (int dd = 0; dd < 6; ++dd) {
                    uint4 xru = *(const uint4*)&xrb[dd*XRR1 + cp];
                    float ev = e[dd];
                    float v0 = fmaf(ev, wa01.x, xla.x + bpk_lo(xru.x)); v0 = fmaxf(v0, 0.01f*v0);
                    float v1 = fmaf(ev, wa01.z, xla.y + bpk_hi(xru.x)); v1 = fmaxf(v1, 0.01f*v1);
                    float v2 = fmaf(ev, wa23.x, xla.z + bpk_lo(xru.y)); v2 = fmaxf(v2, 0.01f*v2);
                    float v3 = fmaf(ev, wa23.z, xla.w + bpk_hi(xru.y)); v3 = fmaxf(v3, 0.01f*v3);
                    float v4 = fmaf(ev, wa45.x, xlb.x + bpk_lo(xru.z)); v4 = fmaxf(v4, 0.01f*v4);
                    float v5 = fmaf(ev, wa45.z, xlb.y + bpk_hi(xru.z)); v5 = fmaxf(v5, 0.01f*v5);
                    float v6 = fmaf(ev, wa67.x, xlb.z + bpk_lo(xru.w)); v6 = fmaxf(v6, 0.01f*v6);
                    float v7 = fmaf(ev, wa67.z, xlb.w + bpk_hi(xru.w)); v7 = fmaxf(v7, 0.01f*v7);
                    float a01 = fmaf(v0, wa01.y, v1*wa01.w);
                    float a23 = fmaf(v2, wa23.y, v3*wa23.w);
                    float a45 = fmaf(v4, wa45.y, v5*wa45.w);
                    float a67 = fmaf(v6, wa67.y, v7*wa67.w);
                    acc[dd] += (a01 + a23) + (a45 + a67);
                }
            }
            #pragma unroll
            for (int dd = 0; dd < 6; ++dd)
                alpha[((d0 + dd)*4 + h)*ASX + s] = acc[dd];
        }
    }
    __syncthreads();
    if (tid < PP*4) {
        float* a = &alpha[tid*ASX];
        float m = -1e30f;
        for (int s = 0; s < PP; ++s) m = fmaxf(m, a[s]);
        float sum = 0.f;
        for (int s = 0; s < PP; ++s) sum += __expf(a[s] - m);
        float inv = 1.f/(sum + 1e-16f);
        for (int s = 0; s < PP; ++s) a[s] = __expf(a[s] - m) * inv;
    }
    __syncthreads();
    float s_loc = 0.f, q_loc = 0.f;
    {
        const int j = tid & 127, h = j >> 5, c = j & 31, d0 = tid >> 7;
        float xlc[PP];
        #pragma unroll
        for (int s = 0; s < PP; ++s) xlc[s] = xl[s*XR1 + h*HP1 + c];
        const float bv = bias1[j];
        #pragma unroll
        for (int k = 0; k < 9; ++k) {
            int d = d0 + 2*k;
            const float* ap = &alpha[(d*4 + h)*ASX];
            float4 a0 = *(const float4*)&ap[0];
            float4 a1 = *(const float4*)&ap[4];
            float4 a2 = *(const float4*)&ap[8];
            float4 a3 = *(const float4*)&ap[12];
            float acc = bv;
            acc = fmaf(a0.x, xlc[0],  acc); acc = fmaf(a0.y, xlc[1],  acc);
            acc = fmaf(a0.z, xlc[2],  acc); acc = fmaf(a0.w, xlc[3],  acc);
            acc = fmaf(a1.x, xlc[4],  acc); acc = fmaf(a1.y, xlc[5],  acc);
            acc = fmaf(a1.z, xlc[6],  acc); acc = fmaf(a1.w, xlc[7],  acc);
            acc = fmaf(a2.x, xlc[8],  acc); acc = fmaf(a2.y, xlc[9],  acc);
            acc = fmaf(a2.z, xlc[10], acc); acc = fmaf(a2.w, xlc[11], acc);
            acc = fmaf(a3.x, xlc[12], acc); acc = fmaf(a3.y, xlc[13], acc);
            acc = fmaf(a3.z, xlc[14], acc); acc = fmaf(a3.w, xlc[15], acc);
            acc = fmaf(ap[16], xlc[16], acc); acc = fmaf(ap[17], xlc[17], acc);
            h1b[(size_t)g*(PP*F1) + d*F1 + j] = f2b(acc);
            s_loc += acc;
            q_loc = fmaf(acc, acc, q_loc);
        }
    }
    __syncthreads();
    wl[tid] = s_loc;
    wr[tid] = q_loc;
    __syncthreads();
    if (tid < F1) {
        atomicAdd(&sum1[tid], wl[tid] + wl[tid + 128]);
        atomicAdd(&ss1[tid],  wr[tid] + wr[tid + 128]);
    }
}

// ================= prep: W2 -> bf16 transposed, bias concat, zero stats =================
__global__ void prep_w(const float* __restrict__ W2l, const float* __restrict__ W2r,
                       const float* __restrict__ b2l, const float* __restrict__ b2r,
                       u16* __restrict__ wbt, float* __restrict__ biascat,
                       float* __restrict__ st)
{
    int t = blockIdx.x*blockDim.x + threadIdx.x;
    if (t < 1536) st[t] = 0.f;
    if (t < 512*128) {
        int c = t >> 7, k = t & 127;
        float v = (c < 256) ? W2l[k*256 + c] : W2r[k*256 + (c-256)];
        wbt[t] = f2b(v);           // wbt[c][k]
    } else if (t < 512*128 + 512) {
        int c = t - 512*128;
        biascat[c] = (c < 256) ? b2l[c] : b2r[c-256];
    }
}

// ================= layer-2 projection GEMM (bn1 finalize + lrelu fused into A-stage) ========
// h1 input is bf16 (halved global loads in A-stage).
__global__ __launch_bounds__(256) void gemm2_kernel(
    const u16* __restrict__ h1b,
    const float* __restrict__ sum1, const float* __restrict__ ss1,
    const float* __restrict__ g1, const float* __restrict__ be1,
    const u16* __restrict__ wbt, const float* __restrict__ biascat, u16* __restrict__ xlr)
{
    __shared__ u16 As[64*128];
    __shared__ u16 Bs[64*128];
    __shared__ float scs[F1], shs[F1];
    const int b = blockIdx.x;
    const int bm = b >> 3, bn = b & 7;
    const int r0 = bm*64, c0 = bn*64;
    const int tid = threadIdx.x;

    if (tid < F1) {
        float mu = sum1[tid] * (1.f/NNODE);
        float var = ss1[tid] * (1.f/NNODE) - mu*mu;
        float s = g1[tid] * rsqrtf(var + 1e-5f);
        scs[tid] = s; shs[tid] = be1[tid] - mu*s;
    }
    __syncthreads();
    for (int i = tid*8; i < 64*128; i += 256*8) {
        int r = i >> 7, c = i & 127;
        uint4 hv = *(const uint4*)&h1b[(size_t)(r0+r)*128 + c];   // 8 bf16
        const u16* pp = (const u16*)&hv;
        short8 a;
        #pragma unroll
        for (int kq = 0; kq < 8; ++kq) {
            float f = b2f(pp[kq]);
            a[kq] = (short)f2b(lrelu(fmaf(scs[c+kq], f, shs[c+kq])));
        }
        int idx = i ^ ((r & 7) << 3);
        *reinterpret_cast<short8*>(&As[idx]) = a;
        *reinterpret_cast<short8*>(&Bs[idx]) =
            *reinterpret_cast<const short8*>(&wbt[(size_t)(c0+r)*128 + c]);
    }
    __syncthreads();

    const int w = tid >> 6, l = tid & 63;
    const int lr = l & 15, lk = (l >> 4) * 8;
    const int ar = w*16 + lr;
    f32x4 acc[4] = {f32x4{0,0,0,0}, f32x4{0,0,0,0}, f32x4{0,0,0,0}, f32x4{0,0,0,0}};

    #pragma unroll
    for (int kk = 0; kk < 4; ++kk) {
        int k0 = kk*32 + lk;
        short8 a = *reinterpret_cast<const short8*>(&As[(ar*128 + k0) ^ ((ar & 7) << 3)]);
        #pragma unroll
        for (int n = 0; n < 4; ++n) {
            int br = n*16 + lr;
            short8 bf = *reinterpret_cast<const short8*>(&Bs[(br*128 + k0) ^ ((br & 7) << 3)]);
            acc[n] = __builtin_amdgcn_mfma_f32_16x16x32_bf16(a, bf, acc[n], 0, 0, 0);
        }
    }
    const int rbase = r0 + w*16 + (l >> 4)*4;
    #pragma unroll
    for (int n = 0; n < 4; ++n) {
        int C = c0 + n*16 + lr;
        float bv = biascat[C];
        #pragma unroll
        for (int j = 0; j < 4; ++j) {
            xlr[(size_t)(rbase + j)*512 + C] = f2b(acc[n][j] + bv);
        }
    }
}

// ================= layer 2 attention + BN2 stats; h2 output stored as bf16 =================
__global__ __launch_bounds__(256) void gat2_attn(
    const u16* __restrict__ xlr, const float* __restrict__ eattr,
    const float* __restrict__ We2, const float* __restrict__ att2,
    const float* __restrict__ bias2, u16* __restrict__ h2b,
    float* __restrict__ sum2, float* __restrict__ ss2)
{
    __shared__ float xl[PP*XR2];
    __shared__ u32 xrp[PP*XRP];
    __shared__ float ea[PP*PP];
    __shared__ float alpha[PP*4*ASX];
    __shared__ float2 wa2[4*HP2];
    const int g = blockIdx.x, tid = threadIdx.x;

    {
        int off = (tid >> 6)*HP2 + (tid & 63);
        wa2[off] = make_float2(We2[tid], att2[tid]);
    }
    for (int i4 = tid; i4 < PP*128; i4 += 256) {
        int i = i4*4, n = i >> 9, j = i & 511;
        const u16* src = &xlr[(size_t)(g*PP + n)*512 + j];
        if (j < 256) {
            ushort4 v = *reinterpret_cast<const ushort4*>(src);
            int off = n*XR2 + (j >> 6)*HP2 + (j & 63);
            *(float4*)&xl[off] = make_float4(b2f(v.x), b2f(v.y), b2f(v.z), b2f(v.w));
        } else {
            uint2 p = *reinterpret_cast<const uint2*>(src);
            int j2 = j & 255;
            int off = n*XRP + (j2 >> 6)*HPP + ((j2 & 63) >> 1);
            *(uint2*)&xrp[off] = p;
        }
    }
    for (int t = tid; t < EPG; t += 256) {
        int s = t/17, pos = t%17;
        int d = pos + (pos >= s);
        ea[s*PP + d] = eattr[g*EPG + t];
    }
    __syncthreads();
    if (tid < PP) {
        float sum = 0.f;
        for (int s = 0; s < PP; ++s) if (s != tid) sum += ea[s*PP + tid];
        ea[tid*PP + tid] = sum * (1.f/17.f);
    }
    __syncthreads();
    {
        const int h = tid & 3, u = tid >> 2;
        const int s = u % PP, q = u / PP;
        if (q < 3) {
            const int d0 = q*6;
            const float* xlrow = &xl[s*XR2 + h*HP2];
            const u32*  xrb    = &xrp[d0*XRP + h*HPP];
            float e[6];
            #pragma unroll
            for (int dd = 0; dd < 6; ++dd) e[dd] = ea[s*PP + d0 + dd];
            float acc[6] = {0,0,0,0,0,0};
            #pragma unroll
            for (int ch = 0; ch < 8; ++ch) {
                const int cc = ch*8, cp = ch*4;
                float4 xla = *(const float4*)&xlrow[cc];
                float4 xlb = *(const float4*)&xlrow[cc + 4];
                float4 wa01 = *(const float4*)&wa2[h*HP2 + cc];
                float4 wa23 = *(const float4*)&wa2[h*HP2 + cc + 2];
                float4 wa45 = *(const float4*)&wa2[h*HP2 + cc + 4];
                float4 wa67 = *(const float4*)&wa2[h*HP2 + cc + 6];
                #pragma unroll
                for (int dd = 0; dd < 6; ++dd) {
                    uint4 xru = *(const uint4*)&xrb[dd*XRP + cp];
                    float ev = e[dd];
                    float v0 = fmaf(ev, wa01.x, xla.x + bpk_lo(xru.x)); v0 = fmaxf(v0, 0.01f*v0);
                    float v1 = fmaf(ev, wa01.z, xla.y + bpk_hi(xru.x)); v1 = fmaxf(v1, 0.01f*v1);
                    float v2 = fmaf(ev, wa23.x, xla.z + bpk_lo(xru.y)); v2 = fmaxf(v2, 0.01f*v2);
                    float v3 = fmaf(ev, wa23.z, xla.w + bpk_hi(xru.y)); v3 = fmaxf(v3, 0.01f*v3);
                    float v4 = fmaf(ev, wa45.x, xlb.x + bpk_lo(xru.z)); v4 = fmaxf(v4, 0.01f*v4);
                    float v5 = fmaf(ev, wa45.z, xlb.y + bpk_hi(xru.z)); v5 = fmaxf(v5, 0.01f*v5);
                    float v6 = fmaf(ev, wa67.x, xlb.z + bpk_lo(xru.w)); v6 = fmaxf(v6, 0.01f*v6);
                    float v7 = fmaf(ev, wa67.z, xlb.w + bpk_hi(xru.w)); v7 = fmaxf(v7, 0.01f*v7);
                    float a01 = fmaf(v0, wa01.y, v1*wa01.w);
                    float a23 = fmaf(v2, wa23.y, v3*wa23.w);
                    float a45 = fmaf(v4, wa45.y, v5*wa45.w);
                    float a67 = fmaf(v6, wa67.y, v7*wa67.w);
                    acc[dd] += (a01 + a23) + (a45 + a67);
                }
            }
            #pragma unroll
            for (int dd = 0; dd < 6; ++dd)
                alpha[((d0 + dd)*4 + h)*ASX + s] = acc[dd];
        }
    }
    __syncthreads();
    if (tid < PP*4) {
        float* a = &alpha[tid*ASX];
        float m = -1e30f;
        for (int s = 0; s < PP; ++s) m = fmaxf(m, a[s]);
        float sum = 0.f;
        for (int s = 0; s < PP; ++s) sum += __expf(a[s] - m);
        float inv = 1.f/(sum + 1e-16f);
        for (int s = 0; s < PP; ++s) a[s] = __expf(a[s] - m) * inv;
    }
    __syncthreads();
    float s_loc = 0.f, q_loc = 0.f;
    {
        const int j = tid, h = j >> 6, c = j & 63;
        float xlc[PP];
        #pragma unroll
        for (int s = 0; s < PP; ++s) xlc[s] = xl[s*XR2 + h*HP2 + c];
        const float bv = bias2[j];
        for (int d = 0; d < PP; ++d) {
            const float* ap = &alpha[(d*4 + h)*ASX];
            float4 a0 = *(const float4*)&ap[0];
            float4 a1 = *(const float4*)&ap[4];
            float4 a2 = *(const float4*)&ap[8];
            float4 a3 = *(const float4*)&ap[12];
            float acc = bv;
            acc = fmaf(a0.x, xlc[0],  acc); acc = fmaf(a0.y, xlc[1],  acc);
            acc = fmaf(a0.z, xlc[2],  acc); acc = fmaf(a0.w, xlc[3],  acc);
            acc = fmaf(a1.x, xlc[4],  acc); acc = fmaf(a1.y, xlc[5],  acc);
            acc = fmaf(a1.z, xlc[6],  acc); acc = fmaf(a1.w, xlc[7],  acc);
            acc = fmaf(a2.x, xlc[8],  acc); acc = fmaf(a2.y, xlc[9],  acc);
            acc = fmaf(a2.z, xlc[10], acc); acc = fmaf(a2.w, xlc[11], acc);
            acc = fmaf(a3.x, xlc[12], acc); acc = fmaf(a3.y, xlc[13], acc);
            acc = fmaf(a3.z, xlc[14], acc); acc = fmaf(a3.w, xlc[15], acc);
            acc = fmaf(ap[16], xlc[16], acc); acc = fmaf(ap[17], xlc[17], acc);
            h2b[(size_t)g*(PP*F2) + d*F2 + j] = f2b(acc);
            s_loc += acc;
            q_loc = fmaf(acc, acc, q_loc);
        }
    }
    atomicAdd(&sum2[tid], s_loc);
    atomicAdd(&ss2[tid], q_loc);
}

// ===== BN2 finalize + lrelu + mean-pool + MLP head; h2 input bf16; 4 graphs/block =====
__global__ __launch_bounds__(512) void mlp_kernel(
    const u16* __restrict__ h2b,
    const float* __restrict__ sum2, const float* __restrict__ ss2,
    const float* __restrict__ g2, const float* __restrict__ be2,
    const float* __restrict__ Wfc1, const float* __restrict__ bfc1,
    const float* __restrict__ Wfc2, const float* __restrict__ bfc2,
    const float* __restrict__ Wfc3, const float* __restrict__ bfc3,
    float* __restrict__ out)
{
    __shared__ float pooled[4][F2];
    __shared__ float y1[4][512];
    __shared__ float part[3][4][128];
    __shared__ float y2[4][128];
    const int g0 = blockIdx.x * 4, tid = threadIdx.x;
    {
        const int col = tid & 255;
        float mu = sum2[col] * (1.f/NNODE);
        float var = ss2[col] * (1.f/NNODE) - mu*mu;
        const float scv = g2[col] * rsqrtf(var + 1e-5f);
        const float shv = be2[col] - mu*scv;
        #pragma unroll
        for (int r = 0; r < 2; ++r) {
            int gi = (tid >> 8) + 2*r;
            float s = 0.f;
            #pragma unroll 3
            for (int n = 0; n < PP; ++n) {
                float hv = b2f(h2b[((size_t)(g0+gi)*PP + n)*F2 + col]);
                float v = fmaf(scv, hv, shv);
                s += fmaxf(v, 0.01f*v);
            }
            pooled[gi][col] = s * (1.f/18.f);
        }
    }
    __syncthreads();
    {
        const int j = tid;
        float acc[4];
        float bv = bfc1[j];
        #pragma unroll
        for (int gi = 0; gi < 4; ++gi) acc[gi] = bv;
        #pragma unroll 8
        for (int k = 0; k < F2; ++k) {
            float w = Wfc1[k*512 + j];
            #pragma unroll
            for (int gi = 0; gi < 4; ++gi) acc[gi] = fmaf(pooled[gi][k], w, acc[gi]);
        }
        #pragma unroll
        for (int gi = 0; gi < 4; ++gi) y1[gi][j] = fmaxf(acc[gi], 0.01f*acc[gi]);
    }
    __syncthreads();
    {
        const int kh = tid >> 7, j = tid & 127;
        float acc[4] = {0,0,0,0};
        #pragma unroll 8
        for (int k = kh*128; k < kh*128 + 128; ++k) {
            float w = Wfc2[k*128 + j];
            #pragma unroll
            for (int gi = 0; gi < 4; ++gi) acc[gi] = fmaf(y1[gi][k], w, acc[gi]);
        }
        if (kh > 0) {
            #pragma unroll
            for (int gi = 0; gi < 4; ++gi) part[kh-1][gi][j] = acc[gi];
        }
        __syncthreads();
        if (kh == 0) {
            float w3 = Wfc3[j], bv = bfc2[j];
            #pragma unroll
            for (int gi = 0; gi < 4; ++gi) {
                float v = acc[gi] + part[0][gi][j] + part[1][gi][j] + part[2][gi][j] + bv;
                y2[gi][j] = fmaxf(v, 0.01f*v) * w3;
            }
        }
    }
    __syncthreads();
    if (tid < 256) {
        int gi = tid >> 6, lx = tid & 63;
        float p = y2[gi][lx] + y2[gi][lx + 64];
        p += __shfl_xor(p, 1); p += __shfl_xor(p, 2); p += __shfl_xor(p, 4);
        p += __shfl_xor(p, 8); p += __shfl_xor(p, 16); p += __shfl_xor(p, 32);
        if (lx == 0) out[g0 + gi] = p + bfc3[0];
    }
}

extern "C" void kernel_launch(void* const* d_in, const int* in_sizes, int n_in,
                              void* d_out, int out_size, void* d_ws, size_t ws_size,
                              hipStream_t stream)
{
    const float* x     = (const float*)d_in[0];
    const float* eattr = (const float*)d_in[1];
    const float* W1l   = (const float*)d_in[4];
    const float* b1l   = (const float*)d_in[5];
    const float* W1r   = (const float*)d_in[6];
    const float* b1r   = (const float*)d_in[7];
    const float* We1   = (const float*)d_in[8];
    const float* att1  = (const float*)d_in[9];
    const float* bias1 = (const float*)d_in[10];
    const float* W2l   = (const float*)d_in[11];
    const float* b2l   = (const float*)d_in[12];
    const float* W2r   = (const float*)d_in[13];
    const float* b2r   = (const float*)d_in[14];
    const float* We2   = (const float*)d_in[15];
    const float* att2  = (const float*)d_in[16];
    const float* bias2 = (const float*)d_in[17];
    const float* g1    = (const float*)d_in[18];
    const float* be1   = (const float*)d_in[19];
    const float* g2    = (const float*)d_in[20];
    const float* be2   = (const float*)d_in[21];
    const float* Wfc1  = (const float*)d_in[22];
    const float* bfc1  = (const float*)d_in[23];
    const float* Wfc2  = (const float*)d_in[24];
    const float* bfc2  = (const float*)d_in[25];
    const float* Wfc3  = (const float*)d_in[26];
    const float* bfc3  = (const float*)d_in[27];
    float* out = (float*)d_out;

    float* ws = (float*)d_ws;
    u16* h1b = (u16*)ws;                             // region sized as NNODE*128 f32 (used half)
    float* h2f = ws + (size_t)NNODE*F1;              // region for h2 (bf16 in-place)
    u16* h2b = (u16*)h2f;
    float* st = h2f + (size_t)NNODE*F2;              // 1536 f32 stats
    float* biascat = st + 1536;                      // 512 f32
    u16* xlr = (u16*)(biascat + 512);                // NNODE*512 bf16
    u16* wbt = xlr + (size_t)NNODE*F2*2;             // 512*128 bf16

    float* sum1 = st,     *ss1 = st+128;
    float* sum2 = st+512, *ss2 = st+768;

    prep_w<<<259, 256, 0, stream>>>(W2l, W2r, b2l, b2r, wbt, biascat, st);
    gat1_kernel<<<GG, 256, 0, stream>>>(x, eattr, W1l, b1l, W1r, b1r, We1, att1, bias1, h1b, sum1, ss1);
    gemm2_kernel<<<(NNODE/64)*8, 256, 0, stream>>>(h1b, sum1, ss1, g1, be1, wbt, biascat, xlr);
    gat2_attn<<<GG, 256, 0, stream>>>(xlr, eattr, We2, att2, bias2, h2b, sum2, ss2);
    mlp_kernel<<<GG/4, 512, 0, stream>>>(h2b, sum2, ss2, g2, be2, Wfc1, bfc1, Wfc2, bfc2, Wfc3, bfc3, out);
}

// Round 20
// 167.967 us; speedup vs baseline: 1.5392x; 1.1616x over previous
//
#include <hip/hip_runtime.h>
#include <cstddef>

#define GG 2048
#define PP 18
#define NNODE (GG*PP)      // 36864
#define EPG 306            // directed edges per graph (17*18)
#define F1 128             // H1*C1
#define F2 256             // H2*C2
#define ASX 20             // alpha row stride: alpha[(d*4+h)*ASX + s]
#define INF 6
// gat1: xl f32 padded layout
#define HP1 36             // xl head stride (f32); also wa1 head stride (float2)
#define XR1 144            // xl row stride; mod 32 = 16
// gat1: xr bf16-PAIR layout (u32 units)
#define HPR1 20
#define XRR1 80            // mod 32 = 16
// gat2: xl f32 padded layout
#define HP2 68
#define XR2 272            // mod 32 = 16
// gat2: xr bf16-PAIR layout (u32 units)
#define HPP 36
#define XRP 144            // mod 32 = 16

typedef unsigned short u16;
typedef unsigned int u32;
typedef __attribute__((ext_vector_type(8))) short short8;   // 8 bf16
typedef __attribute__((ext_vector_type(4))) float f32x4;

__device__ __forceinline__ float lrelu(float v) { return fmaxf(v, 0.01f*v); }

__device__ __forceinline__ u16 f2b(float x) {            // fp32 -> bf16 RNE
    union { float f; unsigned u; } c; c.f = x;
    unsigned r = c.u + 0x7FFF + ((c.u >> 16) & 1);
    return (u16)(r >> 16);
}
__device__ __forceinline__ float b2f(u16 v) {
    union { unsigned u; float f; } c; c.u = ((unsigned)v) << 16;
    return c.f;
}
__device__ __forceinline__ float bpk_lo(u32 u) { return __uint_as_float(u << 16); }
__device__ __forceinline__ float bpk_hi(u32 u) { return __uint_as_float(u & 0xffff0000u); }

// ================= layer 1: GATv2 (6 -> 4x32) + BN1 stats, TWO graphs/block =================
// Per-graph phases identical to R19; sub-block (tid>>8) owns graph 2*blockIdx.x+sub.
// Weights/wa shared across both graphs; 8 waves per barrier-phase.
__global__ __launch_bounds__(512) void gat1_kernel(
    const float* __restrict__ x, const float* __restrict__ eattr,
    const float* __restrict__ W1l, const float* __restrict__ b1l,
    const float* __restrict__ W1r, const float* __restrict__ b1r,
    const float* __restrict__ We1, const float* __restrict__ att1,
    const float* __restrict__ bias1, u16* __restrict__ h1b,
    float* __restrict__ sum1, float* __restrict__ ss1)
{
    __shared__ float xs[2][PP*INF];
    __shared__ float wl[INF*F1], wr[INF*F1];
    __shared__ float bl[F1], br[F1];
    __shared__ float2 wa1[4*HP1];
    __shared__ float ea[2][PP*PP];
    __shared__ float xl[2][PP*XR1];
    __shared__ u32 xrp1[2][PP*XRR1];       // bf16 pairs, [n][h*20 + pair]
    __shared__ float alpha[2][PP*4*ASX];
    __shared__ float sst[512], qst[512];
    const int tid = threadIdx.x;
    const int sub = tid >> 8, tidl = tid & 255;
    const int g = blockIdx.x*2 + sub;

    if (tidl < PP*INF) xs[sub][tidl] = x[(size_t)g*PP*INF + tidl];
    for (int i = tid; i < INF*F1; i += 512) { wl[i] = W1l[i]; wr[i] = W1r[i]; }
    if (tid < F1) {
        bl[tid] = b1l[tid]; br[tid] = b1r[tid];
        int off = (tid >> 5)*HP1 + (tid & 31);
        wa1[off] = make_float2(We1[tid], att1[tid]);
    }
    for (int t = tidl; t < EPG; t += 256) {
        int s = t/17, pos = t%17;
        int d = pos + (pos >= s);
        ea[sub][s*PP + d] = eattr[(size_t)g*EPG + t];
    }
    __syncthreads();
    if (tidl < PP) {
        float sum = 0.f;
        for (int s = 0; s < PP; ++s) if (s != tidl) sum += ea[sub][s*PP + tidl];
        ea[sub][tidl*PP + tidl] = sum * (1.f/17.f);
    }
    __syncthreads();
    // projections: weight columns hoisted to registers; xl f32, xr bf16
    {
        const int j = tidl & 127;
        float wlr[INF], wrr[INF];
        #pragma unroll
        for (int k = 0; k < INF; ++k) { wlr[k] = wl[k*F1 + j]; wrr[k] = wr[k*F1 + j]; }
        const float blv = bl[j], brv = br[j];
        u16* xr16 = (u16*)&xrp1[sub][0];
        const int xloff = (j >> 5)*HP1 + (j & 31);
        const int xroff = (j >> 5)*(2*HPR1) + (j & 31);
        for (int o = tidl; o < PP*F1; o += 256) {
            int n = o >> 7;
            float al = blv, ar = brv;
            #pragma unroll
            for (int k = 0; k < INF; ++k) {
                float xv = xs[sub][n*INF + k];
                al = fmaf(xv, wlr[k], al);
                ar = fmaf(xv, wrr[k], ar);
            }
            xl[sub][n*XR1 + xloff] = al;
            xr16[n*(2*XRR1) + xroff] = f2b(ar);
        }
    }
    __syncthreads();
    // alpha: (fixed s, fixed h, 6 d); 8-c chunks; xl f32 b128, xr bf16-pair uint4
    {
        const int h = tidl & 3, u = tidl >> 2;
        const int s = u % PP, q = u / PP;
        if (q < 3) {
            const int d0 = q*6;
            const float* xlrow = &xl[sub][s*XR1 + h*HP1];
            const u32*  xrb    = &xrp1[sub][d0*XRR1 + h*HPR1];
            float e[6];
            #pragma unroll
            for (int dd = 0; dd < 6; ++dd) e[dd] = ea[sub][s*PP + d0 + dd];
            float acc[6] = {0,0,0,0,0,0};
            #pragma unroll
            for (int ch = 0; ch < 4; ++ch) {           // 8 c per chunk
                const int cc = ch*8, cp = ch*4;
                float4 xla = *(const float4*)&xlrow[cc];
                float4 xlb = *(const float4*)&xlrow[cc + 4];
                float4 wa01 = *(const float4*)&wa1[h*HP1 + cc];
                float4 wa23 = *(const float4*)&wa1[h*HP1 + cc + 2];
                float4 wa45 = *(const float4*)&wa1[h*HP1 + cc + 4];
                float4 wa67 = *(const float4*)&wa1[h*HP1 + cc + 6];
                #pragma unroll
                for (int dd = 0; dd < 6; ++dd) {
                    uint4 xru = *(const uint4*)&xrb[dd*XRR1 + cp];
                    float ev = e[dd];
                    float v0 = fmaf(ev, wa01.x, xla.x + bpk_lo(xru.x)); v0 = fmaxf(v0, 0.01f*v0);
                    float v1 = fmaf(ev, wa01.z, xla.y + bpk_hi(xru.x)); v1 = fmaxf(v1, 0.01f*v1);
                    float v2 = fmaf(ev, wa23.x, xla.z + bpk_lo(xru.y)); v2 = fmaxf(v2, 0.01f*v2);
                    float v3 = fmaf(ev, wa23.z, xla.w + bpk_hi(xru.y)); v3 = fmaxf(v3, 0.01f*v3);
                    float v4 = fmaf(ev, wa45.x, xlb.x + bpk_lo(xru.z)); v4 = fmaxf(v4, 0.01f*v4);
                    float v5 = fmaf(ev, wa45.z, xlb.y + bpk_hi(xru.z)); v5 = fmaxf(v5, 0.01f*v5);
                    float v6 = fmaf(ev, wa67.x, xlb.z + bpk_lo(xru.w)); v6 = fmaxf(v6, 0.01f*v6);
                    float v7 = fmaf(ev, wa67.z, xlb.w + bpk_hi(xru.w)); v7 = fmaxf(v7, 0.01f*v7);
                    float a01 = fmaf(v0, wa01.y, v1*wa01.w);
                    float a23 = fmaf(v2, wa23.y, v3*wa23.w);
                    float a45 = fmaf(v4, wa45.y, v5*wa45.w);
                    float a67 = fmaf(v6, wa67.y, v7*wa67.w);
                    acc[dd] += (a01 + a23) + (a45 + a67);
                }
            }
            #pragma unroll
            for (int dd = 0; dd < 6; ++dd)
                alpha[sub][((d0 + dd)*4 + h)*ASX + s] = acc[dd];
        }
    }
    __syncthreads();
    if (tidl < PP*4) {
        float* a = &alpha[sub][tidl*ASX];
        float m = -1e30f;
        for (int s = 0; s < PP; ++s) m = fmaxf(m, a[s]);
        float sum = 0.f;
        for (int s = 0; s < PP; ++s) sum += __expf(a[s] - m);
        float inv = 1.f/(sum + 1e-16f);
        for (int s = 0; s < PP; ++s) a[s] = __expf(a[s] - m) * inv;
    }
    __syncthreads();
    float s_loc = 0.f, q_loc = 0.f;
    {
        const int j = tidl & 127, h = j >> 5, c = j & 31, d0 = tidl >> 7;
        float xlc[PP];
        #pragma unroll
        for (int s = 0; s < PP; ++s) xlc[s] = xl[sub][s*XR1 + h*HP1 + c];
        const float bv = bias1[j];
        #pragma unroll
        for (int k = 0; k < 9; ++k) {
            int d = d0 + 2*k;
            const float* ap = &alpha[sub][(d*4 + h)*ASX];
            float4 a0 = *(const float4*)&ap[0];
            float4 a1 = *(const float4*)&ap[4];
            float4 a2 = *(const float4*)&ap[8];
            float4 a3 = *(const float4*)&ap[12];
            float acc = bv;
            acc = fmaf(a0.x, xlc[0],  acc); acc = fmaf(a0.y, xlc[1],  acc);
            acc = fmaf(a0.z, xlc[2],  acc); acc = fmaf(a0.w, xlc[3],  acc);
            acc = fmaf(a1.x, xlc[4],  acc); acc = fmaf(a1.y, xlc[5],  acc);
            acc = fmaf(a1.z, xlc[6],  acc); acc = fmaf(a1.w, xlc[7],  acc);
            acc = fmaf(a2.x, xlc[8],  acc); acc = fmaf(a2.y, xlc[9],  acc);
            acc = fmaf(a2.z, xlc[10], acc); acc = fmaf(a2.w, xlc[11], acc);
            acc = fmaf(a3.x, xlc[12], acc); acc = fmaf(a3.y, xlc[13], acc);
            acc = fmaf(a3.z, xlc[14], acc); acc = fmaf(a3.w, xlc[15], acc);
            acc = fmaf(ap[16], xlc[16], acc); acc = fmaf(ap[17], xlc[17], acc);
            h1b[(size_t)g*(PP*F1) + d*F1 + j] = f2b(acc);
            s_loc += acc;
            q_loc = fmaf(acc, acc, q_loc);
        }
    }
    __syncthreads();
    sst[tid] = s_loc;
    qst[tid] = q_loc;
    __syncthreads();
    if (tid < F1) {
        atomicAdd(&sum1[tid], ((sst[tid] + sst[tid+128]) + (sst[tid+256] + sst[tid+384])));
        atomicAdd(&ss1[tid],  ((qst[tid] + qst[tid+128]) + (qst[tid+256] + qst[tid+384])));
    }
}

// ================= prep: W2 -> bf16 transposed, bias concat, zero stats =================
__global__ void prep_w(const float* __restrict__ W2l, const float* __restrict__ W2r,
                       const float* __restrict__ b2l, const float* __restrict__ b2r,
                       u16* __restrict__ wbt, float* __restrict__ biascat,
                       float* __restrict__ st)
{
    int t = blockIdx.x*blockDim.x + threadIdx.x;
    if (t < 1536) st[t] = 0.f;
    if (t < 512*128) {
        int c = t >> 7, k = t & 127;
        float v = (c < 256) ? W2l[k*256 + c] : W2r[k*256 + (c-256)];
        wbt[t] = f2b(v);           // wbt[c][k]
    } else if (t < 512*128 + 512) {
        int c = t - 512*128;
        biascat[c] = (c < 256) ? b2l[c] : b2r[c-256];
    }
}

// ================= layer-2 projection GEMM (bn1 finalize + lrelu fused into A-stage) ========
__global__ __launch_bounds__(256) void gemm2_kernel(
    const u16* __restrict__ h1b,
    const float* __restrict__ sum1, const float* __restrict__ ss1,
    const float* __restrict__ g1, const float* __restrict__ be1,
    const u16* __restrict__ wbt, const float* __restrict__ biascat, u16* __restrict__ xlr)
{
    __shared__ u16 As[64*128];
    __shared__ u16 Bs[64*128];
    __shared__ float scs[F1], shs[F1];
    const int b = blockIdx.x;
    const int bm = b >> 3, bn = b & 7;
    const int r0 = bm*64, c0 = bn*64;
    const int tid = threadIdx.x;

    if (tid < F1) {
        float mu = sum1[tid] * (1.f/NNODE);
        float var = ss1[tid] * (1.f/NNODE) - mu*mu;
        float s = g1[tid] * rsqrtf(var + 1e-5f);
        scs[tid] = s; shs[tid] = be1[tid] - mu*s;
    }
    __syncthreads();
    for (int i = tid*8; i < 64*128; i += 256*8) {
        int r = i >> 7, c = i & 127;
        uint4 hv = *(const uint4*)&h1b[(size_t)(r0+r)*128 + c];   // 8 bf16
        const u16* pp = (const u16*)&hv;
        short8 a;
        #pragma unroll
        for (int kq = 0; kq < 8; ++kq) {
            float f = b2f(pp[kq]);
            a[kq] = (short)f2b(lrelu(fmaf(scs[c+kq], f, shs[c+kq])));
        }
        int idx = i ^ ((r & 7) << 3);
        *reinterpret_cast<short8*>(&As[idx]) = a;
        *reinterpret_cast<short8*>(&Bs[idx]) =
            *reinterpret_cast<const short8*>(&wbt[(size_t)(c0+r)*128 + c]);
    }
    __syncthreads();

    const int w = tid >> 6, l = tid & 63;
    const int lr = l & 15, lk = (l >> 4) * 8;
    const int ar = w*16 + lr;
    f32x4 acc[4] = {f32x4{0,0,0,0}, f32x4{0,0,0,0}, f32x4{0,0,0,0}, f32x4{0,0,0,0}};

    #pragma unroll
    for (int kk = 0; kk < 4; ++kk) {
        int k0 = kk*32 + lk;
        short8 a = *reinterpret_cast<const short8*>(&As[(ar*128 + k0) ^ ((ar & 7) << 3)]);
        #pragma unroll
        for (int n = 0; n < 4; ++n) {
            int br = n*16 + lr;
            short8 bf = *reinterpret_cast<const short8*>(&Bs[(br*128 + k0) ^ ((br & 7) << 3)]);
            acc[n] = __builtin_amdgcn_mfma_f32_16x16x32_bf16(a, bf, acc[n], 0, 0, 0);
        }
    }
    const int rbase = r0 + w*16 + (l >> 4)*4;
    #pragma unroll
    for (int n = 0; n < 4; ++n) {
        int C = c0 + n*16 + lr;
        float bv = biascat[C];
        #pragma unroll
        for (int j = 0; j < 4; ++j) {
            xlr[(size_t)(rbase + j)*512 + C] = f2b(acc[n][j] + bv);
        }
    }
}

// ================= layer 2 attention + BN2 stats; h2 output stored as bf16 =================
__global__ __launch_bounds__(256) void gat2_attn(
    const u16* __restrict__ xlr, const float* __restrict__ eattr,
    const float* __restrict__ We2, const float* __restrict__ att2,
    const float* __restrict__ bias2, u16* __restrict__ h2b,
    float* __restrict__ sum2, float* __restrict__ ss2)
{
    __shared__ float xl[PP*XR2];
    __shared__ u32 xrp[PP*XRP];
    __shared__ float ea[PP*PP];
    __shared__ float alpha[PP*4*ASX];
    __shared__ float2 wa2[4*HP2];
    const int g = blockIdx.x, tid = threadIdx.x;

    {
        int off = (tid >> 6)*HP2 + (tid & 63);
        wa2[off] = make_float2(We2[tid], att2[tid]);
    }
    for (int i4 = tid; i4 < PP*128; i4 += 256) {
        int i = i4*4, n = i >> 9, j = i & 511;
        const u16* src = &xlr[(size_t)(g*PP + n)*512 + j];
        if (j < 256) {
            ushort4 v = *reinterpret_cast<const ushort4*>(src);
            int off = n*XR2 + (j >> 6)*HP2 + (j & 63);
            *(float4*)&xl[off] = make_float4(b2f(v.x), b2f(v.y), b2f(v.z), b2f(v.w));
        } else {
            uint2 p = *reinterpret_cast<const uint2*>(src);
            int j2 = j & 255;
            int off = n*XRP + (j2 >> 6)*HPP + ((j2 & 63) >> 1);
            *(uint2*)&xrp[off] = p;
        }
    }
    for (int t = tid; t < EPG; t += 256) {
        int s = t/17, pos = t%17;
        int d = pos + (pos >= s);
        ea[s*PP + d] = eattr[(size_t)g*EPG + t];
    }
    __syncthreads();
    if (tid < PP) {
        float sum = 0.f;
        for (int s = 0; s < PP; ++s) if (s != tid) sum += ea[s*PP + tid];
        ea[tid*PP + tid] = sum * (1.f/17.f);
    }
    __syncthreads();
    {
        const int h = tid & 3, u = tid >> 2;
        const int s = u % PP, q = u / PP;
        if (q < 3) {
            const int d0 = q*6;
            const float* xlrow = &xl[s*XR2 + h*HP2];
            const u32*  xrb    = &xrp[d0*XRP + h*HPP];
            float e[6];
            #pragma unroll
            for (int dd = 0; dd < 6; ++dd) e[dd] = ea[s*PP + d0 + dd];
            float acc[6] = {0,0,0,0,0,0};
            #pragma unroll
            for (int ch = 0; ch < 8; ++ch) {
                const int cc = ch*8, cp = ch*4;
                float4 xla = *(const float4*)&xlrow[cc];
                float4 xlb = *(const float4*)&xlrow[cc + 4];
                float4 wa01 = *(const float4*)&wa2[h*HP2 + cc];
                float4 wa23 = *(const float4*)&wa2[h*HP2 + cc + 2];
                float4 wa45 = *(const float4*)&wa2[h*HP2 + cc + 4];
                float4 wa67 = *(const float4*)&wa2[h*HP2 + cc + 6];
                #pragma unroll
                for (int dd = 0; dd < 6; ++dd) {
                    uint4 xru = *(const uint4*)&xrb[dd*XRP + cp];
                    float ev = e[dd];
                    float v0 = fmaf(ev, wa01.x, xla.x + bpk_lo(xru.x)); v0 = fmaxf(v0, 0.01f*v0);
                    float v1 = fmaf(ev, wa01.z, xla.y + bpk_hi(xru.x)); v1 = fmaxf(v1, 0.01f*v1);
                    float v2 = fmaf(ev, wa23.x, xla.z + bpk_lo(xru.y)); v2 = fmaxf(v2, 0.01f*v2);
                    float v3 = fmaf(ev, wa23.z, xla.w + bpk_hi(xru.y)); v3 = fmaxf(v3, 0.01f*v3);
                    float v4 = fmaf(ev, wa45.x, xlb.x + bpk_lo(xru.z)); v4 = fmaxf(v4, 0.01f*v4);
                    float v5 = fmaf(ev, wa45.z, xlb.y + bpk_hi(xru.z)); v5 = fmaxf(v5, 0.01f*v5);
                    float v6 = fmaf(ev, wa67.x, xlb.z + bpk_lo(xru.w)); v6 = fmaxf(v6, 0.01f*v6);
                    float v7 = fmaf(ev, wa67.z, xlb.w + bpk_hi(xru.w)); v7 = fmaxf(v7, 0.01f*v7);
                    float a01 = fmaf(v0, wa01.y, v1*wa01.w);
                    float a23 = fmaf(v2, wa23.y, v3*wa23.w);
                    float a45 = fmaf(v4, wa45.y, v5*wa45.w);
                    float a67 = fmaf(v6, wa67.y, v7*wa67.w);
                    acc[dd] += (a01 + a23) + (a45 + a67);
                }
            }
            #pragma unroll
            for (int dd = 0; dd < 6; ++dd)
                alpha[((d0 + dd)*4 + h)*ASX + s] = acc[dd];
        }
    }
    __syncthreads();
    if (tid < PP*4) {
        float* a = &alpha[tid*ASX];
        float m = -1e30f;
        for (int s = 0; s < PP; ++s) m = fmaxf(m, a[s]);
        float sum = 0.f;
        for (int s = 0; s < PP; ++s) sum += __expf(a[s] - m);
        float inv = 1.f/(sum + 1e-16f);
        for (int s = 0; s < PP; ++s) a[s] = __expf(a[s] - m) * inv;
    }
    __syncthreads();
    float s_loc = 0.f, q_loc = 0.f;
    {
        const int j = tid, h = j >> 6, c = j & 63;
        float xlc[PP];
        #pragma unroll
        for (int s = 0; s < PP; ++s) xlc[s] = xl[s*XR2 + h*HP2 + c];
        const float bv = bias2[j];
        for (int d = 0; d < PP; ++d) {
            const float* ap = &alpha[(d*4 + h)*ASX];
            float4 a0 = *(const float4*)&ap[0];
            float4 a1 = *(const float4*)&ap[4];
            float4 a2 = *(const float4*)&ap[8];
            float4 a3 = *(const float4*)&ap[12];
            float acc = bv;
            acc = fmaf(a0.x, xlc[0],  acc); acc = fmaf(a0.y, xlc[1],  acc);
            acc = fmaf(a0.z, xlc[2],  acc); acc = fmaf(a0.w, xlc[3],  acc);
            acc = fmaf(a1.x, xlc[4],  acc); acc = fmaf(a1.y, xlc[5],  acc);
            acc = fmaf(a1.z, xlc[6],  acc); acc = fmaf(a1.w, xlc[7],  acc);
            acc = fmaf(a2.x, xlc[8],  acc); acc = fmaf(a2.y, xlc[9],  acc);
            acc = fmaf(a2.z, xlc[10], acc); acc = fmaf(a2.w, xlc[11], acc);
            acc = fmaf(a3.x, xlc[12], acc); acc = fmaf(a3.y, xlc[13], acc);
            acc = fmaf(a3.z, xlc[14], acc); acc = fmaf(a3.w, xlc[15], acc);
            acc = fmaf(ap[16], xlc[16], acc); acc = fmaf(ap[17], xlc[17], acc);
            h2b[(size_t)g*(PP*F2) + d*F2 + j] = f2b(acc);
            s_loc += acc;
            q_loc = fmaf(acc, acc, q_loc);
        }
    }
    atomicAdd(&sum2[tid], s_loc);
    atomicAdd(&ss2[tid], q_loc);
}

// ===== BN2 finalize + lrelu + mean-pool + MLP head; h2 input bf16; 4 graphs/block =====
__global__ __launch_bounds__(512) void mlp_kernel(
    const u16* __restrict__ h2b,
    const float* __restrict__ sum2, const float* __restrict__ ss2,
    const float* __restrict__ g2, const float* __restrict__ be2,
    const float* __restrict__ Wfc1, const float* __restrict__ bfc1,
    const float* __restrict__ Wfc2, const float* __restrict__ bfc2,
    const float* __restrict__ Wfc3, const float* __restrict__ bfc3,
    float* __restrict__ out)
{
    __shared__ float pooled[4][F2];
    __shared__ float y1[4][512];
    __shared__ float part[3][4][128];
    __shared__ float y2[4][128];
    const int g0 = blockIdx.x * 4, tid = threadIdx.x;
    {
        const int col = tid & 255;
        float mu = sum2[col] * (1.f/NNODE);
        float var = ss2[col] * (1.f/NNODE) - mu*mu;
        const float scv = g2[col] * rsqrtf(var + 1e-5f);
        const float shv = be2[col] - mu*scv;
        #pragma unroll
        for (int r = 0; r < 2; ++r) {
            int gi = (tid >> 8) + 2*r;
            float s = 0.f;
            #pragma unroll 3
            for (int n = 0; n < PP; ++n) {
                float hv = b2f(h2b[((size_t)(g0+gi)*PP + n)*F2 + col]);
                float v = fmaf(scv, hv, shv);
                s += fmaxf(v, 0.01f*v);
            }
            pooled[gi][col] = s * (1.f/18.f);
        }
    }
    __syncthreads();
    {
        const int j = tid;
        float acc[4];
        float bv = bfc1[j];
        #pragma unroll
        for (int gi = 0; gi < 4; ++gi) acc[gi] = bv;
        #pragma unroll 8
        for (int k = 0; k < F2; ++k) {
            float w = Wfc1[k*512 + j];
            #pragma unroll
            for (int gi = 0; gi < 4; ++gi) acc[gi] = fmaf(pooled[gi][k], w, acc[gi]);
        }
        #pragma unroll
        for (int gi = 0; gi < 4; ++gi) y1[gi][j] = fmaxf(acc[gi], 0.01f*acc[gi]);
    }
    __syncthreads();
    {
        const int kh = tid >> 7, j = tid & 127;
        float acc[4] = {0,0,0,0};
        #pragma unroll 8
        for (int k = kh*128; k < kh*128 + 128; ++k) {
            float w = Wfc2[k*128 + j];
            #pragma unroll
            for (int gi = 0; gi < 4; ++gi) acc[gi] = fmaf(y1[gi][k], w, acc[gi]);
        }
        if (kh > 0) {
            #pragma unroll
            for (int gi = 0; gi < 4; ++gi) part[kh-1][gi][j] = acc[gi];
        }
        __syncthreads();
        if (kh == 0) {
            float w3 = Wfc3[j], bv = bfc2[j];
            #pragma unroll
            for (int gi = 0; gi < 4; ++gi) {
                float v = acc[gi] + part[0][gi][j] + part[1][gi][j] + part[2][gi][j] + bv;
                y2[gi][j] = fmaxf(v, 0.01f*v) * w3;
            }
        }
    }
    __syncthreads();
    if (tid < 256) {
        int gi = tid >> 6, lx = tid & 63;
        float p = y2[gi][lx] + y2[gi][lx + 64];
        p += __shfl_xor(p, 1); p += __shfl_xor(p, 2); p += __shfl_xor(p, 4);
        p += __shfl_xor(p, 8); p += __shfl_xor(p, 16); p += __shfl_xor(p, 32);
        if (lx == 0) out[g0 + gi] = p + bfc3[0];
    }
}

extern "C" void kernel_launch(void* const* d_in, const int* in_sizes, int n_in,
                              void* d_out, int out_size, void* d_ws, size_t ws_size,
                              hipStream_t stream)
{
    const float* x     = (const float*)d_in[0];
    const float* eattr = (const float*)d_in[1];
    const float* W1l   = (const float*)d_in[4];
    const float* b1l   = (const float*)d_in[5];
    const float* W1r   = (const float*)d_in[6];
    const float* b1r   = (const float*)d_in[7];
    const float* We1   = (const float*)d_in[8];
    const float* att1  = (const float*)d_in[9];
    const float* bias1 = (const float*)d_in[10];
    const float* W2l   = (const float*)d_in[11];
    const float* b2l   = (const float*)d_in[12];
    const float* W2r   = (const float*)d_in[13];
    const float* b2r   = (const float*)d_in[14];
    const float* We2   = (const float*)d_in[15];
    const float* att2  = (const float*)d_in[16];
    const float* bias2 = (const float*)d_in[17];
    const float* g1    = (const float*)d_in[18];
    const float* be1   = (const float*)d_in[19];
    const float* g2    = (const float*)d_in[20];
    const float* be2   = (const float*)d_in[21];
    const float* Wfc1  = (const float*)d_in[22];
    const float* bfc1  = (const float*)d_in[23];
    const float* Wfc2  = (const float*)d_in[24];
    const float* bfc2  = (const float*)d_in[25];
    const float* Wfc3  = (const float*)d_in[26];
    const float* bfc3  = (const float*)d_in[27];
    float* out = (float*)d_out;

    float* ws = (float*)d_ws;
    u16* h1b = (u16*)ws;                             // region sized as NNODE*128 f32 (used half)
    float* h2f = ws + (size_t)NNODE*F1;              // region for h2 (bf16 in-place)
    u16* h2b = (u16*)h2f;
    float* st = h2f + (size_t)NNODE*F2;              // 1536 f32 stats
    float* biascat = st + 1536;                      // 512 f32
    u16* xlr = (u16*)(biascat + 512);                // NNODE*512 bf16
    u16* wbt = xlr + (size_t)NNODE*F2*2;             // 512*128 bf16

    float* sum1 = st,     *ss1 = st+128;
    float* sum2 = st+512, *ss2 = st+768;

    prep_w<<<259, 256, 0, stream>>>(W2l, W2r, b2l, b2r, wbt, biascat, st);
    gat1_kernel<<<GG/2, 512, 0, stream>>>(x, eattr, W1l, b1l, W1r, b1r, We1, att1, bias1, h1b, sum1, ss1);
    gemm2_kernel<<<(NNODE/64)*8, 256, 0, stream>>>(h1b, sum1, ss1, g1, be1, wbt, biascat, xlr);
    gat2_attn<<<GG, 256, 0, stream>>>(xlr, eattr, We2, att2, bias2, h2b, sum2, ss2);
    mlp_kernel<<<GG/4, 512, 0, stream>>>(h2b, sum2, ss2, g2, be2, Wfc1, bfc1, Wfc2, bfc2, Wfc3, bfc3, out);
}